// Round 1
// baseline (880.196 us; speedup 1.0000x reference)
//
#include <hip/hip_runtime.h>
#include <math.h>

#define Bb 16
#define Nn 2048
#define Ff 2048
#define Ee 128
#define Kk 10

// ---------------- helpers ----------------
__device__ inline float wave_sum(float x) {
    for (int o = 32; o; o >>= 1) x += __shfl_down(x, o);
    return x;  // valid in lane 0
}

// ---------------- K1: hop projections h[rj][b][e] = rel[b] @ W[rj] + bias ----------------
__global__ void k_hops(const float* __restrict__ rel, const float* __restrict__ hop_W,
                       const float* __restrict__ hop_b, float* __restrict__ h) {
    int rj = blockIdx.x;      // 0..3  (r*2 + j)
    int b  = blockIdx.y;
    int e  = threadIdx.x;     // 0..127
    const float* W  = hop_W + (size_t)rj * Ee * Ee;
    const float* rb = rel + b * Ee;
    float acc = hop_b[rj * Ee + e];
    for (int i = 0; i < Ee; ++i) acc += rb[i] * W[i * Ee + e];
    h[((size_t)rj * Bb + b) * Ee + e] = acc;
}

// ---------------- K2: entity self-norms ----------------
__global__ void k_entnorm(const float* __restrict__ ent, float* __restrict__ ent_norm) {
    int row  = blockIdx.x * 4 + (threadIdx.x >> 6);   // B*N rows
    int lane = threadIdx.x & 63;
    const float* p = ent + (size_t)row * Ee;
    float a = p[lane], c = p[lane + 64];
    float s = wave_sum(a * a + c * c);
    if (lane == 0) ent_norm[row] = s;
}

// ---------------- K3: per-fact query distances -> c0,c1,s2b0,s2b1,lsc0 ----------------
__global__ void k_facts(const float* __restrict__ rel, const float* __restrict__ arg1,
                        const float* __restrict__ arg2, const float* __restrict__ frel,
                        const float* __restrict__ fa1, const float* __restrict__ fa2,
                        const float* __restrict__ h, const int* __restrict__ nb_facts,
                        float* __restrict__ c0, float* __restrict__ c1,
                        float* __restrict__ s2b0, float* __restrict__ s2b1,
                        float* __restrict__ lsc0) {
    int f = blockIdx.x, b = blockIdx.y;
    int lane = threadIdx.x;            // block = 64
    size_t fb = ((size_t)b * Ff + f) * Ee;
    float d_rr = 0, d_a11 = 0, d_a22 = 0, d_h10 = 0, d_h11 = 0, d_h20 = 0, d_h21 = 0;
    float d_a12 = 0, d_a21 = 0, n1 = 0, n2 = 0;
#pragma unroll
    for (int half = 0; half < 2; ++half) {
        int e = lane + half * 64;
        float vr = frel[fb + e], v1 = fa1[fb + e], v2 = fa2[fb + e];
        float qr = rel[b * Ee + e], q1 = arg1[b * Ee + e], q2 = arg2[b * Ee + e];
        float h10 = h[((size_t)0 * Bb + b) * Ee + e];
        float h20 = h[((size_t)1 * Bb + b) * Ee + e];
        float h11 = h[((size_t)2 * Bb + b) * Ee + e];
        float h21 = h[((size_t)3 * Bb + b) * Ee + e];
        float t;
        t = qr - vr;  d_rr  += t * t;
        t = q1 - v1;  d_a11 += t * t;
        t = q2 - v2;  d_a22 += t * t;
        t = h10 - vr; d_h10 += t * t;
        t = h11 - vr; d_h11 += t * t;
        t = h20 - vr; d_h20 += t * t;
        t = h21 - vr; d_h21 += t * t;
        t = q1 - v2;  d_a12 += t * t;
        t = q2 - v1;  d_a21 += t * t;
        n1 += v1 * v1; n2 += v2 * v2;
    }
    d_rr = wave_sum(d_rr);   d_a11 = wave_sum(d_a11); d_a22 = wave_sum(d_a22);
    d_h10 = wave_sum(d_h10); d_h11 = wave_sum(d_h11); d_h20 = wave_sum(d_h20);
    d_h21 = wave_sum(d_h21); d_a12 = wave_sum(d_a12); d_a21 = wave_sum(d_a21);
    n1 = wave_sum(n1);       n2 = wave_sum(n2);
    if (lane == 0) {
        bool valid = f < nb_facts[b];
        const float NI = -INFINITY;
        size_t o = (size_t)b * Ff + f;
        lsc0[o] = valid ? -0.5f * (d_rr + d_a11 + d_a22) : NI;
        // r=0: kr = kern(h1_0, fact_rel)*kern(arg1, fact_arg1); kE vs fact_arg2
        c0[o]   = valid ? (-0.5f * (d_h10 + d_a11 + n2)) : NI;
        // r=1: kr = kern(h1_1, fact_rel)*kern(arg1, fact_arg2); kE vs fact_arg1
        c1[o]   = valid ? (-0.5f * (d_h11 + d_a12 + n1)) : NI;
        // r=0 second hop: kern(h2_0,frel)*kern(z,fa1)*kern(arg2,fa2)
        s2b0[o] = valid ? (-0.5f * (d_h20 + d_a22)) : NI;
        // r=1 second hop: kern(h2_1,frel)*kern(arg2,fa1)*kern(z,fa2)
        s2b1[o] = valid ? (-0.5f * (d_h21 + d_a21)) : NI;
    }
}

// ---------------- K4: fused bias+max GEMM: sp[b,n] = mask * exp(max_f(c[f] + e.f) - 0.5*|e|^2) ----
#define TN 64
#define TF 64
#define TE 16
#define LDP 68   // TN+4 padded stride (272B, 16B-aligned rows)

__global__ __launch_bounds__(256) void k_spmax(
    const float* __restrict__ ent, const float* __restrict__ fa1,
    const float* __restrict__ fa2, const float* __restrict__ c0,
    const float* __restrict__ c1, const float* __restrict__ ent_norm,
    const int* __restrict__ nb_entities, float* __restrict__ sp0,
    float* __restrict__ sp1) {
    int nblk = blockIdx.x;   // N/TN
    int b    = blockIdx.y;
    int r    = blockIdx.z;
    const float* factX = (r == 0) ? fa2 : fa1;
    const float* cb    = ((r == 0) ? c0 : c1) + (size_t)b * Ff;
    float* sp          = ((r == 0) ? sp0 : sp1) + (size_t)b * Nn;

    __shared__ float As[Ee][LDP];   // full 64xE A tile, e-major
    __shared__ float Bs[TE][LDP];

    int tid = threadIdx.x;
    int tx = tid & 15, ty = tid >> 4;

    // stage A tile once (64 rows x 128 e)
    {
        const float* Ab = ent + ((size_t)b * Nn + (size_t)nblk * TN) * Ee;
        for (int s = tid; s < TN * Ee / 4; s += 256) {
            int row = s >> 5;            // E/4 = 32 float4 per row
            int c4  = (s & 31) * 4;
            float4 v = *(const float4*)(Ab + (size_t)row * Ee + c4);
            As[c4 + 0][row] = v.x;
            As[c4 + 1][row] = v.y;
            As[c4 + 2][row] = v.z;
            As[c4 + 3][row] = v.w;
        }
    }

    float mmax[4] = {-INFINITY, -INFINITY, -INFINITY, -INFINITY};

    for (int f0 = 0; f0 < Ff; f0 += TF) {
        float acc[4][4] = {};
        const float* Bbp = factX + ((size_t)b * Ff + f0) * Ee;
        for (int e0 = 0; e0 < Ee; e0 += TE) {
            __syncthreads();
            {   // stage B chunk: TF rows x TE e  (256 float4 slots)
                int row = tid >> 2;          // TE/4 = 4 float4 per row
                int c4  = (tid & 3) * 4;
                float4 v = *(const float4*)(Bbp + (size_t)row * Ee + e0 + c4);
                Bs[c4 + 0][row] = v.x;
                Bs[c4 + 1][row] = v.y;
                Bs[c4 + 2][row] = v.z;
                Bs[c4 + 3][row] = v.w;
            }
            __syncthreads();
#pragma unroll
            for (int e = 0; e < TE; ++e) {
                float4 a  = *(const float4*)&As[e0 + e][ty * 4];
                float4 bv = *(const float4*)&Bs[e][tx * 4];
                float ar[4] = {a.x, a.y, a.z, a.w};
                float br[4] = {bv.x, bv.y, bv.z, bv.w};
#pragma unroll
                for (int i = 0; i < 4; ++i)
#pragma unroll
                    for (int j = 0; j < 4; ++j) acc[i][j] += ar[i] * br[j];
            }
        }
#pragma unroll
        for (int j = 0; j < 4; ++j) {
            float c = cb[f0 + tx * 4 + j];
#pragma unroll
            for (int i = 0; i < 4; ++i) mmax[i] = fmaxf(mmax[i], c + acc[i][j]);
        }
    }

    // reduce max across the 16 tx columns
    __syncthreads();
    float* red = &As[0][0];   // reuse: need 64*16 floats
#pragma unroll
    for (int i = 0; i < 4; ++i) red[(ty * 4 + i) * 16 + tx] = mmax[i];
    __syncthreads();
    if (tid < TN) {
        float m = red[tid * 16];
#pragma unroll
        for (int j = 1; j < 16; ++j) m = fmaxf(m, red[tid * 16 + j]);
        int n = nblk * TN + tid;
        float v = (n < nb_entities[b]) ? expf(m - 0.5f * ent_norm[(size_t)b * Nn + n]) : 0.0f;
        sp[n] = v;
    }
}

// ---------------- K5: top-K per (b, r), stable-descending like jax.lax.top_k ----------------
__global__ void k_topk(const float* __restrict__ sp0, const float* __restrict__ sp1,
                       float* __restrict__ z_scores, int* __restrict__ z_idx) {
    int b = blockIdx.x, r = blockIdx.y;
    const float* sp = ((r == 0) ? sp0 : sp1) + (size_t)b * Nn;
    __shared__ float vals[Nn];
    __shared__ float bv[256];
    __shared__ int   bi[256];
    int tid = threadIdx.x;
    for (int i = tid; i < Nn; i += 256) vals[i] = sp[i];
    __syncthreads();
    for (int k = 0; k < Kk; ++k) {
        float best = -1.0f; int bidx = Nn;
        for (int i = tid; i < Nn; i += 256) {
            float v = vals[i];
            if (v > best) { best = v; bidx = i; }
        }
        bv[tid] = best; bi[tid] = bidx;
        __syncthreads();
        for (int s = 128; s > 0; s >>= 1) {
            if (tid < s) {
                float v2 = bv[tid + s]; int i2 = bi[tid + s];
                if (v2 > bv[tid] || (v2 == bv[tid] && i2 < bi[tid])) { bv[tid] = v2; bi[tid] = i2; }
            }
            __syncthreads();
        }
        if (tid == 0) {
            z_scores[((size_t)b * 2 + r) * Kk + k] = bv[0];
            z_idx[((size_t)b * 2 + r) * Kk + k]    = bi[0];
            vals[bi[0]] = -1.0f;
        }
        __syncthreads();
    }
}

// ---------------- K6: second hop rescore + min(tnorm) ----------------
__global__ void k_s2(const float* __restrict__ ent, const float* __restrict__ fa1,
                     const float* __restrict__ fa2, const float* __restrict__ s2b0,
                     const float* __restrict__ s2b1, const float* __restrict__ z_scores,
                     const int* __restrict__ z_idx, float* __restrict__ rules) {
    int b = blockIdx.x, k = blockIdx.y, r = blockIdx.z;
    const float* factX = (r == 0) ? fa1 : fa2;   // z compares vs fa1 (r=0) / fa2 (r=1)
    const float* s2b   = ((r == 0) ? s2b0 : s2b1) + (size_t)b * Ff;
    int zi   = z_idx[((size_t)b * 2 + r) * Kk + k];
    int wv   = threadIdx.x >> 6, lane = threadIdx.x & 63;
    const float* z = ent + ((size_t)b * Nn + zi) * Ee;
    float z0 = z[lane], z1 = z[lane + 64];
    float lmax = -INFINITY;
    for (int f = wv; f < Ff; f += 4) {
        const float* fp = factX + ((size_t)b * Ff + f) * Ee;
        float d0 = z0 - fp[lane], d1 = z1 - fp[lane + 64];
        float s = wave_sum(d0 * d0 + d1 * d1);
        if (lane == 0) lmax = fmaxf(lmax, s2b[f] - 0.5f * s);
    }
    __shared__ float red[4];
    if (lane == 0) red[wv] = lmax;
    __syncthreads();
    if (threadIdx.x == 0) {
        float m = fmaxf(fmaxf(red[0], red[1]), fmaxf(red[2], red[3]));
        size_t o = ((size_t)b * 2 + r) * Kk + k;
        rules[o] = fminf(expf(m), z_scores[o]);
    }
}

// ---------------- K7: final combine ----------------
__global__ void k_final(const float* __restrict__ lsc0, const float* __restrict__ rules,
                        float* __restrict__ out) {
    int b = blockIdx.x, tid = threadIdx.x;
    __shared__ float sm[256];
    float m = -INFINITY;
    for (int f = tid; f < Ff; f += 256) m = fmaxf(m, lsc0[(size_t)b * Ff + f]);
    sm[tid] = m;
    __syncthreads();
    for (int s = 128; s > 0; s >>= 1) {
        if (tid < s) sm[tid] = fmaxf(sm[tid], sm[tid + s]);
        __syncthreads();
    }
    if (tid == 0) {
        float sc0 = expf(sm[0]);
        float g = -INFINITY;
        for (int i = 0; i < 2 * Kk; ++i) g = fmaxf(g, rules[(size_t)b * 2 * Kk + i]);
        out[b] = fmaxf(sc0, g);
    }
}

extern "C" void kernel_launch(void* const* d_in, const int* in_sizes, int n_in,
                              void* d_out, int out_size, void* d_ws, size_t ws_size,
                              hipStream_t stream) {
    const float* rel  = (const float*)d_in[0];
    const float* arg1 = (const float*)d_in[1];
    const float* arg2 = (const float*)d_in[2];
    const float* frel = (const float*)d_in[3];
    const float* fa1  = (const float*)d_in[4];
    const float* fa2  = (const float*)d_in[5];
    const float* ent  = (const float*)d_in[6];
    const float* hopW = (const float*)d_in[7];
    const float* hopb = (const float*)d_in[8];
    const int* nb_facts    = (const int*)d_in[9];
    const int* nb_entities = (const int*)d_in[10];
    float* out = (float*)d_out;

    float* ws = (float*)d_ws;
    size_t off = 0;
    float* h        = ws + off; off += 4 * Bb * Ee;       // 8192
    float* c0       = ws + off; off += (size_t)Bb * Ff;
    float* c1       = ws + off; off += (size_t)Bb * Ff;
    float* s2b0     = ws + off; off += (size_t)Bb * Ff;
    float* s2b1     = ws + off; off += (size_t)Bb * Ff;
    float* lsc0     = ws + off; off += (size_t)Bb * Ff;
    float* sp0      = ws + off; off += (size_t)Bb * Nn;
    float* sp1      = ws + off; off += (size_t)Bb * Nn;
    float* ent_norm = ws + off; off += (size_t)Bb * Nn;
    float* z_scores = ws + off; off += Bb * 2 * Kk;
    float* rules    = ws + off; off += Bb * 2 * Kk;
    int*   z_idx    = (int*)(ws + off); off += Bb * 2 * Kk;

    k_hops<<<dim3(4, Bb), 128, 0, stream>>>(rel, hopW, hopb, h);
    k_entnorm<<<dim3(Bb * Nn / 4), 256, 0, stream>>>(ent, ent_norm);
    k_facts<<<dim3(Ff, Bb), 64, 0, stream>>>(rel, arg1, arg2, frel, fa1, fa2, h,
                                             nb_facts, c0, c1, s2b0, s2b1, lsc0);
    k_spmax<<<dim3(Nn / TN, Bb, 2), 256, 0, stream>>>(ent, fa1, fa2, c0, c1, ent_norm,
                                                      nb_entities, sp0, sp1);
    k_topk<<<dim3(Bb, 2), 256, 0, stream>>>(sp0, sp1, z_scores, z_idx);
    k_s2<<<dim3(Bb, Kk, 2), 256, 0, stream>>>(ent, fa1, fa2, s2b0, s2b1, z_scores,
                                              z_idx, rules);
    k_final<<<dim3(Bb), 256, 0, stream>>>(lsc0, rules, out);
}

// Round 2
// 537.385 us; speedup vs baseline: 1.6379x; 1.6379x over previous
//
#include <hip/hip_runtime.h>
#include <math.h>

#define Bb 16
#define Nn 2048
#define Ff 2048
#define Ee 128
#define Kk 10

typedef __attribute__((ext_vector_type(8))) short short8;
typedef __attribute__((ext_vector_type(4))) float f32x4;

// ---------------- helpers ----------------
__device__ inline float wave_sum(float x) {
    for (int o = 32; o; o >>= 1) x += __shfl_down(x, o);
    return x;  // valid in lane 0
}

// split fp32 -> bf16 hi (truncate) + bf16 lo (truncate of exact remainder)
__device__ inline void bsplit(float x, unsigned short& h, unsigned short& l) {
    unsigned int u = __float_as_uint(x);
    h = (unsigned short)(u >> 16);
    float hf = __uint_as_float(u & 0xFFFF0000u);
    l = (unsigned short)(__float_as_uint(x - hf) >> 16);
}

// ---------------- K1: hop projections h[rj][b][e] = rel[b] @ W[rj] + bias ----------------
__global__ void k_hops(const float* __restrict__ rel, const float* __restrict__ hop_W,
                       const float* __restrict__ hop_b, float* __restrict__ h) {
    int rj = blockIdx.x;      // 0..3  (r*2 + j)
    int b  = blockIdx.y;
    int e  = threadIdx.x;     // 0..127
    const float* W  = hop_W + (size_t)rj * Ee * Ee;
    const float* rb = rel + b * Ee;
    float acc = hop_b[rj * Ee + e];
    for (int i = 0; i < Ee; ++i) acc += rb[i] * W[i * Ee + e];
    h[((size_t)rj * Bb + b) * Ee + e] = acc;
}

// ---------------- K2: entity self-norms ----------------
__global__ void k_entnorm(const float* __restrict__ ent, float* __restrict__ ent_norm) {
    int row  = blockIdx.x * 4 + (threadIdx.x >> 6);   // B*N rows
    int lane = threadIdx.x & 63;
    const float* p = ent + (size_t)row * Ee;
    float a = p[lane], c = p[lane + 64];
    float s = wave_sum(a * a + c * c);
    if (lane == 0) ent_norm[row] = s;
}

// ---------------- K3: per-fact query distances -> c0,c1,s2b0,s2b1,lsc0 ----------------
__global__ void k_facts(const float* __restrict__ rel, const float* __restrict__ arg1,
                        const float* __restrict__ arg2, const float* __restrict__ frel,
                        const float* __restrict__ fa1, const float* __restrict__ fa2,
                        const float* __restrict__ h, const int* __restrict__ nb_facts,
                        float* __restrict__ c0, float* __restrict__ c1,
                        float* __restrict__ s2b0, float* __restrict__ s2b1,
                        float* __restrict__ lsc0) {
    int f = blockIdx.x, b = blockIdx.y;
    int lane = threadIdx.x;            // block = 64
    size_t fb = ((size_t)b * Ff + f) * Ee;
    float d_rr = 0, d_a11 = 0, d_a22 = 0, d_h10 = 0, d_h11 = 0, d_h20 = 0, d_h21 = 0;
    float d_a12 = 0, d_a21 = 0, n1 = 0, n2 = 0;
#pragma unroll
    for (int half = 0; half < 2; ++half) {
        int e = lane + half * 64;
        float vr = frel[fb + e], v1 = fa1[fb + e], v2 = fa2[fb + e];
        float qr = rel[b * Ee + e], q1 = arg1[b * Ee + e], q2 = arg2[b * Ee + e];
        float h10 = h[((size_t)0 * Bb + b) * Ee + e];
        float h20 = h[((size_t)1 * Bb + b) * Ee + e];
        float h11 = h[((size_t)2 * Bb + b) * Ee + e];
        float h21 = h[((size_t)3 * Bb + b) * Ee + e];
        float t;
        t = qr - vr;  d_rr  += t * t;
        t = q1 - v1;  d_a11 += t * t;
        t = q2 - v2;  d_a22 += t * t;
        t = h10 - vr; d_h10 += t * t;
        t = h11 - vr; d_h11 += t * t;
        t = h20 - vr; d_h20 += t * t;
        t = h21 - vr; d_h21 += t * t;
        t = q1 - v2;  d_a12 += t * t;
        t = q2 - v1;  d_a21 += t * t;
        n1 += v1 * v1; n2 += v2 * v2;
    }
    d_rr = wave_sum(d_rr);   d_a11 = wave_sum(d_a11); d_a22 = wave_sum(d_a22);
    d_h10 = wave_sum(d_h10); d_h11 = wave_sum(d_h11); d_h20 = wave_sum(d_h20);
    d_h21 = wave_sum(d_h21); d_a12 = wave_sum(d_a12); d_a21 = wave_sum(d_a21);
    n1 = wave_sum(n1);       n2 = wave_sum(n2);
    if (lane == 0) {
        bool valid = f < nb_facts[b];
        const float NI = -INFINITY;
        size_t o = (size_t)b * Ff + f;
        lsc0[o] = valid ? -0.5f * (d_rr + d_a11 + d_a22) : NI;
        c0[o]   = valid ? (-0.5f * (d_h10 + d_a11 + n2)) : NI;
        c1[o]   = valid ? (-0.5f * (d_h11 + d_a12 + n1)) : NI;
        s2b0[o] = valid ? (-0.5f * (d_h20 + d_a22)) : NI;
        s2b1[o] = valid ? (-0.5f * (d_h21 + d_a21)) : NI;
    }
}

// ---------------- K4: fused bias+max GEMM via split-bf16 MFMA ----------------
// sp[b,n] = mask * exp(max_f(c[f] + e_n.f_f) - 0.5*|e_n|^2)
// A (entities) fragments held in registers (hi+lo), B (facts) staged hi/lo in LDS.
#define BMs 128
#define BFs 64
#define LDB 136   // padded k-stride in bf16 elems (272 B rows, 16B aligned)

__global__ __launch_bounds__(256, 2) void k_spmax_mfma(
    const float* __restrict__ ent, const float* __restrict__ fa1,
    const float* __restrict__ fa2, const float* __restrict__ c0,
    const float* __restrict__ c1, const float* __restrict__ ent_norm,
    const int* __restrict__ nb_entities, float* __restrict__ sp0,
    float* __restrict__ sp1) {
    int nblk = blockIdx.x, b = blockIdx.y, r = blockIdx.z;
    const float* factX = (r == 0) ? fa2 : fa1;
    const float* cb = ((r == 0) ? c0 : c1) + (size_t)b * Ff;
    float* sp = ((r == 0) ? sp0 : sp1) + (size_t)b * Nn;

    __shared__ unsigned short Bh[BFs * LDB];
    __shared__ unsigned short Bl[BFs * LDB];
    __shared__ float csh[BFs];

    int tid = threadIdx.x;
    int wave = tid >> 6, lane = tid & 63;
    int wm = wave >> 1, wn = wave & 1;
    int lane15 = lane & 15, quad = lane >> 4;

    // ---- A fragments in registers (hi/lo split), reused across all facts ----
    short8 ah[4][4], al[4][4];
    {
        const float* abase = ent + ((size_t)b * Nn + (size_t)nblk * BMs + wm * 64) * Ee;
#pragma unroll
        for (int i = 0; i < 4; ++i)
#pragma unroll
            for (int ks = 0; ks < 4; ++ks) {
                const float* p = abase + (size_t)(i * 16 + lane15) * Ee + ks * 32 + quad * 8;
                float4 v0 = *(const float4*)p;
                float4 v1 = *(const float4*)(p + 4);
                float xs[8] = {v0.x, v0.y, v0.z, v0.w, v1.x, v1.y, v1.z, v1.w};
#pragma unroll
                for (int j = 0; j < 8; ++j) {
                    unsigned short hh, ll;
                    bsplit(xs[j], hh, ll);
                    ah[i][ks][j] = (short)hh;
                    al[i][ks][j] = (short)ll;
                }
            }
    }

    float mmax[4][4];
#pragma unroll
    for (int i = 0; i < 4; ++i)
#pragma unroll
        for (int rr = 0; rr < 4; ++rr) mmax[i][rr] = -INFINITY;

    for (int f0 = 0; f0 < Ff; f0 += BFs) {
        // ---- stage B chunk (hi/lo bf16) + bias chunk ----
        {
            int rt = tid >> 2;               // 0..63 fact row
            int kq = (tid & 3) * 32;         // k quarter
            const float* src = factX + ((size_t)b * Ff + f0 + rt) * Ee + kq;
            unsigned short* bhp = &Bh[rt * LDB + kq];
            unsigned short* blp = &Bl[rt * LDB + kq];
#pragma unroll
            for (int c = 0; c < 8; ++c) {
                float4 v = *(const float4*)(src + c * 4);
                unsigned short h0, h1, h2, h3, l0, l1, l2, l3;
                bsplit(v.x, h0, l0); bsplit(v.y, h1, l1);
                bsplit(v.z, h2, l2); bsplit(v.w, h3, l3);
                uint2 ph = make_uint2((unsigned)h0 | ((unsigned)h1 << 16),
                                      (unsigned)h2 | ((unsigned)h3 << 16));
                uint2 pl = make_uint2((unsigned)l0 | ((unsigned)l1 << 16),
                                      (unsigned)l2 | ((unsigned)l3 << 16));
                *(uint2*)(bhp + c * 4) = ph;
                *(uint2*)(blp + c * 4) = pl;
            }
            if (tid < BFs) csh[tid] = cb[f0 + tid];
        }
        __syncthreads();

        f32x4 acc[4][2];
#pragma unroll
        for (int i = 0; i < 4; ++i)
#pragma unroll
            for (int j = 0; j < 2; ++j) acc[i][j] = (f32x4){0.f, 0.f, 0.f, 0.f};

#pragma unroll
        for (int ks = 0; ks < 4; ++ks) {
            int kb = ks * 32 + quad * 8;
            short8 bh0 = *(const short8*)&Bh[(wn * 32 + lane15) * LDB + kb];
            short8 bl0 = *(const short8*)&Bl[(wn * 32 + lane15) * LDB + kb];
            short8 bh1 = *(const short8*)&Bh[(wn * 32 + 16 + lane15) * LDB + kb];
            short8 bl1 = *(const short8*)&Bl[(wn * 32 + 16 + lane15) * LDB + kb];
#pragma unroll
            for (int i = 0; i < 4; ++i) {
                acc[i][0] = __builtin_amdgcn_mfma_f32_16x16x32_bf16(ah[i][ks], bh0, acc[i][0], 0, 0, 0);
                acc[i][0] = __builtin_amdgcn_mfma_f32_16x16x32_bf16(al[i][ks], bh0, acc[i][0], 0, 0, 0);
                acc[i][0] = __builtin_amdgcn_mfma_f32_16x16x32_bf16(ah[i][ks], bl0, acc[i][0], 0, 0, 0);
                acc[i][1] = __builtin_amdgcn_mfma_f32_16x16x32_bf16(ah[i][ks], bh1, acc[i][1], 0, 0, 0);
                acc[i][1] = __builtin_amdgcn_mfma_f32_16x16x32_bf16(al[i][ks], bh1, acc[i][1], 0, 0, 0);
                acc[i][1] = __builtin_amdgcn_mfma_f32_16x16x32_bf16(ah[i][ks], bl1, acc[i][1], 0, 0, 0);
            }
        }

#pragma unroll
        for (int j = 0; j < 2; ++j) {
            float cj = csh[wn * 32 + j * 16 + lane15];
#pragma unroll
            for (int i = 0; i < 4; ++i)
#pragma unroll
                for (int rr = 0; rr < 4; ++rr)
                    mmax[i][rr] = fmaxf(mmax[i][rr], acc[i][j][rr] + cj);
        }
        __syncthreads();
    }

    // ---- reduce row maxima across lane-columns and wn waves (reuse Bh as scratch) ----
    float* red = (float*)Bh;   // [128][33]
#pragma unroll
    for (int i = 0; i < 4; ++i)
#pragma unroll
        for (int rr = 0; rr < 4; ++rr) {
            int row = wm * 64 + i * 16 + quad * 4 + rr;
            red[row * 33 + wn * 16 + lane15] = mmax[i][rr];
        }
    __syncthreads();
    if (tid < BMs) {
        float m = red[tid * 33];
#pragma unroll
        for (int c = 1; c < 32; ++c) m = fmaxf(m, red[tid * 33 + c]);
        int n = nblk * BMs + tid;
        float v = (n < nb_entities[b]) ? expf(m - 0.5f * ent_norm[(size_t)b * Nn + n]) : 0.0f;
        sp[n] = v;
    }
}

// ---------------- K5: top-K per (b, r), stable-descending like jax.lax.top_k ----------------
__global__ void k_topk(const float* __restrict__ sp0, const float* __restrict__ sp1,
                       float* __restrict__ z_scores, int* __restrict__ z_idx) {
    int b = blockIdx.x, r = blockIdx.y;
    const float* sp = ((r == 0) ? sp0 : sp1) + (size_t)b * Nn;
    __shared__ float vals[Nn];
    __shared__ float bv[256];
    __shared__ int   bi[256];
    int tid = threadIdx.x;
    for (int i = tid; i < Nn; i += 256) vals[i] = sp[i];
    __syncthreads();
    for (int k = 0; k < Kk; ++k) {
        float best = -1.0f; int bidx = Nn;
        for (int i = tid; i < Nn; i += 256) {
            float v = vals[i];
            if (v > best) { best = v; bidx = i; }
        }
        bv[tid] = best; bi[tid] = bidx;
        __syncthreads();
        for (int s = 128; s > 0; s >>= 1) {
            if (tid < s) {
                float v2 = bv[tid + s]; int i2 = bi[tid + s];
                if (v2 > bv[tid] || (v2 == bv[tid] && i2 < bi[tid])) { bv[tid] = v2; bi[tid] = i2; }
            }
            __syncthreads();
        }
        if (tid == 0) {
            z_scores[((size_t)b * 2 + r) * Kk + k] = bv[0];
            z_idx[((size_t)b * 2 + r) * Kk + k]    = bi[0];
            vals[bi[0]] = -1.0f;
        }
        __syncthreads();
    }
}

// ---------------- K6: second hop rescore + min(tnorm) ----------------
__global__ void k_s2(const float* __restrict__ ent, const float* __restrict__ fa1,
                     const float* __restrict__ fa2, const float* __restrict__ s2b0,
                     const float* __restrict__ s2b1, const float* __restrict__ z_scores,
                     const int* __restrict__ z_idx, float* __restrict__ rules) {
    int b = blockIdx.x, k = blockIdx.y, r = blockIdx.z;
    const float* factX = (r == 0) ? fa1 : fa2;   // z compares vs fa1 (r=0) / fa2 (r=1)
    const float* s2b   = ((r == 0) ? s2b0 : s2b1) + (size_t)b * Ff;
    int zi   = z_idx[((size_t)b * 2 + r) * Kk + k];
    int wv   = threadIdx.x >> 6, lane = threadIdx.x & 63;
    const float* z = ent + ((size_t)b * Nn + zi) * Ee;
    float z0 = z[lane], z1 = z[lane + 64];
    float lmax = -INFINITY;
    for (int f = wv; f < Ff; f += 4) {
        const float* fp = factX + ((size_t)b * Ff + f) * Ee;
        float d0 = z0 - fp[lane], d1 = z1 - fp[lane + 64];
        float s = wave_sum(d0 * d0 + d1 * d1);
        if (lane == 0) lmax = fmaxf(lmax, s2b[f] - 0.5f * s);
    }
    __shared__ float red[4];
    if (lane == 0) red[wv] = lmax;
    __syncthreads();
    if (threadIdx.x == 0) {
        float m = fmaxf(fmaxf(red[0], red[1]), fmaxf(red[2], red[3]));
        size_t o = ((size_t)b * 2 + r) * Kk + k;
        rules[o] = fminf(expf(m), z_scores[o]);
    }
}

// ---------------- K7: final combine ----------------
__global__ void k_final(const float* __restrict__ lsc0, const float* __restrict__ rules,
                        float* __restrict__ out) {
    int b = blockIdx.x, tid = threadIdx.x;
    __shared__ float sm[256];
    float m = -INFINITY;
    for (int f = tid; f < Ff; f += 256) m = fmaxf(m, lsc0[(size_t)b * Ff + f]);
    sm[tid] = m;
    __syncthreads();
    for (int s = 128; s > 0; s >>= 1) {
        if (tid < s) sm[tid] = fmaxf(sm[tid], sm[tid + s]);
        __syncthreads();
    }
    if (tid == 0) {
        float sc0 = expf(sm[0]);
        float g = -INFINITY;
        for (int i = 0; i < 2 * Kk; ++i) g = fmaxf(g, rules[(size_t)b * 2 * Kk + i]);
        out[b] = fmaxf(sc0, g);
    }
}

extern "C" void kernel_launch(void* const* d_in, const int* in_sizes, int n_in,
                              void* d_out, int out_size, void* d_ws, size_t ws_size,
                              hipStream_t stream) {
    const float* rel  = (const float*)d_in[0];
    const float* arg1 = (const float*)d_in[1];
    const float* arg2 = (const float*)d_in[2];
    const float* frel = (const float*)d_in[3];
    const float* fa1  = (const float*)d_in[4];
    const float* fa2  = (const float*)d_in[5];
    const float* ent  = (const float*)d_in[6];
    const float* hopW = (const float*)d_in[7];
    const float* hopb = (const float*)d_in[8];
    const int* nb_facts    = (const int*)d_in[9];
    const int* nb_entities = (const int*)d_in[10];
    float* out = (float*)d_out;

    float* ws = (float*)d_ws;
    size_t off = 0;
    float* h        = ws + off; off += 4 * Bb * Ee;
    float* c0       = ws + off; off += (size_t)Bb * Ff;
    float* c1       = ws + off; off += (size_t)Bb * Ff;
    float* s2b0     = ws + off; off += (size_t)Bb * Ff;
    float* s2b1     = ws + off; off += (size_t)Bb * Ff;
    float* lsc0     = ws + off; off += (size_t)Bb * Ff;
    float* sp0      = ws + off; off += (size_t)Bb * Nn;
    float* sp1      = ws + off; off += (size_t)Bb * Nn;
    float* ent_norm = ws + off; off += (size_t)Bb * Nn;
    float* z_scores = ws + off; off += Bb * 2 * Kk;
    float* rules    = ws + off; off += Bb * 2 * Kk;
    int*   z_idx    = (int*)(ws + off); off += Bb * 2 * Kk;

    k_hops<<<dim3(4, Bb), 128, 0, stream>>>(rel, hopW, hopb, h);
    k_entnorm<<<dim3(Bb * Nn / 4), 256, 0, stream>>>(ent, ent_norm);
    k_facts<<<dim3(Ff, Bb), 64, 0, stream>>>(rel, arg1, arg2, frel, fa1, fa2, h,
                                             nb_facts, c0, c1, s2b0, s2b1, lsc0);
    k_spmax_mfma<<<dim3(Nn / BMs, Bb, 2), 256, 0, stream>>>(ent, fa1, fa2, c0, c1, ent_norm,
                                                            nb_entities, sp0, sp1);
    k_topk<<<dim3(Bb, 2), 256, 0, stream>>>(sp0, sp1, z_scores, z_idx);
    k_s2<<<dim3(Bb, Kk, 2), 256, 0, stream>>>(ent, fa1, fa2, s2b0, s2b1, z_scores,
                                              z_idx, rules);
    k_final<<<dim3(Bb), 256, 0, stream>>>(lsc0, rules, out);
}

// Round 3
// 298.136 us; speedup vs baseline: 2.9523x; 1.8025x over previous
//
#include <hip/hip_runtime.h>
#include <math.h>

#define Bb 16
#define Nn 2048
#define Ff 2048
#define Ee 128
#define Kk 10
#define S2FC 8              // fact chunks in k_s2
#define S2F (Ff / S2FC)     // 256 facts per block

typedef __attribute__((ext_vector_type(8))) short short8;
typedef __attribute__((ext_vector_type(4))) float f32x4;

// ---------------- helpers ----------------
__device__ inline float wave_sum(float x) {
    for (int o = 32; o; o >>= 1) x += __shfl_down(x, o);
    return x;  // valid in lane 0
}

// split fp32 -> bf16 hi (truncate) + bf16 lo (truncate of exact remainder)
__device__ inline void bsplit(float x, unsigned short& h, unsigned short& l) {
    unsigned int u = __float_as_uint(x);
    h = (unsigned short)(u >> 16);
    float hf = __uint_as_float(u & 0xFFFF0000u);
    l = (unsigned short)(__float_as_uint(x - hf) >> 16);
}

// ---------------- K1: hop projections h[rj][b][e] = rel[b] @ W[rj] + bias ----------------
__global__ void k_hops(const float* __restrict__ rel, const float* __restrict__ hop_W,
                       const float* __restrict__ hop_b, float* __restrict__ h) {
    int rj = blockIdx.x;      // 0..3  (r*2 + j)
    int b  = blockIdx.y;
    int e  = threadIdx.x;     // 0..127
    const float* W  = hop_W + (size_t)rj * Ee * Ee;
    const float* rb = rel + b * Ee;
    float acc = hop_b[rj * Ee + e];
    for (int i = 0; i < Ee; ++i) acc += rb[i] * W[i * Ee + e];
    h[((size_t)rj * Bb + b) * Ee + e] = acc;
}

// ---------------- K2: entity self-norms ----------------
__global__ void k_entnorm(const float* __restrict__ ent, float* __restrict__ ent_norm) {
    int row  = blockIdx.x * 4 + (threadIdx.x >> 6);   // B*N rows
    int lane = threadIdx.x & 63;
    const float* p = ent + (size_t)row * Ee;
    float a = p[lane], c = p[lane + 64];
    float s = wave_sum(a * a + c * c);
    if (lane == 0) ent_norm[row] = s;
}

// ---------------- K3: per-fact query distances -> c0,c1,s2b0,s2b1,lsc0 ----------------
__global__ void k_facts(const float* __restrict__ rel, const float* __restrict__ arg1,
                        const float* __restrict__ arg2, const float* __restrict__ frel,
                        const float* __restrict__ fa1, const float* __restrict__ fa2,
                        const float* __restrict__ h, const int* __restrict__ nb_facts,
                        float* __restrict__ c0, float* __restrict__ c1,
                        float* __restrict__ s2b0, float* __restrict__ s2b1,
                        float* __restrict__ lsc0) {
    int f = blockIdx.x, b = blockIdx.y;
    int lane = threadIdx.x;            // block = 64
    size_t fb = ((size_t)b * Ff + f) * Ee;
    float d_rr = 0, d_a11 = 0, d_a22 = 0, d_h10 = 0, d_h11 = 0, d_h20 = 0, d_h21 = 0;
    float d_a12 = 0, d_a21 = 0, n1 = 0, n2 = 0;
#pragma unroll
    for (int half = 0; half < 2; ++half) {
        int e = lane + half * 64;
        float vr = frel[fb + e], v1 = fa1[fb + e], v2 = fa2[fb + e];
        float qr = rel[b * Ee + e], q1 = arg1[b * Ee + e], q2 = arg2[b * Ee + e];
        float h10 = h[((size_t)0 * Bb + b) * Ee + e];
        float h20 = h[((size_t)1 * Bb + b) * Ee + e];
        float h11 = h[((size_t)2 * Bb + b) * Ee + e];
        float h21 = h[((size_t)3 * Bb + b) * Ee + e];
        float t;
        t = qr - vr;  d_rr  += t * t;
        t = q1 - v1;  d_a11 += t * t;
        t = q2 - v2;  d_a22 += t * t;
        t = h10 - vr; d_h10 += t * t;
        t = h11 - vr; d_h11 += t * t;
        t = h20 - vr; d_h20 += t * t;
        t = h21 - vr; d_h21 += t * t;
        t = q1 - v2;  d_a12 += t * t;
        t = q2 - v1;  d_a21 += t * t;
        n1 += v1 * v1; n2 += v2 * v2;
    }
    d_rr = wave_sum(d_rr);   d_a11 = wave_sum(d_a11); d_a22 = wave_sum(d_a22);
    d_h10 = wave_sum(d_h10); d_h11 = wave_sum(d_h11); d_h20 = wave_sum(d_h20);
    d_h21 = wave_sum(d_h21); d_a12 = wave_sum(d_a12); d_a21 = wave_sum(d_a21);
    n1 = wave_sum(n1);       n2 = wave_sum(n2);
    if (lane == 0) {
        bool valid = f < nb_facts[b];
        const float NI = -INFINITY;
        size_t o = (size_t)b * Ff + f;
        lsc0[o] = valid ? -0.5f * (d_rr + d_a11 + d_a22) : NI;
        c0[o]   = valid ? (-0.5f * (d_h10 + d_a11 + n2)) : NI;
        c1[o]   = valid ? (-0.5f * (d_h11 + d_a12 + n1)) : NI;
        s2b0[o] = valid ? (-0.5f * (d_h20 + d_a22)) : NI;
        s2b1[o] = valid ? (-0.5f * (d_h21 + d_a21)) : NI;
    }
}

// ---------------- K4: fused bias+max GEMM via split-bf16 MFMA ----------------
#define BMs 128
#define BFs 64
#define LDB 136   // padded k-stride in bf16 elems (272 B rows, 16B aligned)

__global__ __launch_bounds__(256, 2) void k_spmax_mfma(
    const float* __restrict__ ent, const float* __restrict__ fa1,
    const float* __restrict__ fa2, const float* __restrict__ c0,
    const float* __restrict__ c1, const float* __restrict__ ent_norm,
    const int* __restrict__ nb_entities, float* __restrict__ sp0,
    float* __restrict__ sp1) {
    int nblk = blockIdx.x, b = blockIdx.y, r = blockIdx.z;
    const float* factX = (r == 0) ? fa2 : fa1;
    const float* cb = ((r == 0) ? c0 : c1) + (size_t)b * Ff;
    float* sp = ((r == 0) ? sp0 : sp1) + (size_t)b * Nn;

    __shared__ unsigned short Bh[BFs * LDB];
    __shared__ unsigned short Bl[BFs * LDB];
    __shared__ float csh[BFs];

    int tid = threadIdx.x;
    int wave = tid >> 6, lane = tid & 63;
    int wm = wave >> 1, wn = wave & 1;
    int lane15 = lane & 15, quad = lane >> 4;

    short8 ah[4][4], al[4][4];
    {
        const float* abase = ent + ((size_t)b * Nn + (size_t)nblk * BMs + wm * 64) * Ee;
#pragma unroll
        for (int i = 0; i < 4; ++i)
#pragma unroll
            for (int ks = 0; ks < 4; ++ks) {
                const float* p = abase + (size_t)(i * 16 + lane15) * Ee + ks * 32 + quad * 8;
                float4 v0 = *(const float4*)p;
                float4 v1 = *(const float4*)(p + 4);
                float xs[8] = {v0.x, v0.y, v0.z, v0.w, v1.x, v1.y, v1.z, v1.w};
#pragma unroll
                for (int j = 0; j < 8; ++j) {
                    unsigned short hh, ll;
                    bsplit(xs[j], hh, ll);
                    ah[i][ks][j] = (short)hh;
                    al[i][ks][j] = (short)ll;
                }
            }
    }

    float mmax[4][4];
#pragma unroll
    for (int i = 0; i < 4; ++i)
#pragma unroll
        for (int rr = 0; rr < 4; ++rr) mmax[i][rr] = -INFINITY;

    for (int f0 = 0; f0 < Ff; f0 += BFs) {
        {
            int rt = tid >> 2;               // 0..63 fact row
            int kq = (tid & 3) * 32;         // k quarter
            const float* src = factX + ((size_t)b * Ff + f0 + rt) * Ee + kq;
            unsigned short* bhp = &Bh[rt * LDB + kq];
            unsigned short* blp = &Bl[rt * LDB + kq];
#pragma unroll
            for (int c = 0; c < 8; ++c) {
                float4 v = *(const float4*)(src + c * 4);
                unsigned short h0, h1, h2, h3, l0, l1, l2, l3;
                bsplit(v.x, h0, l0); bsplit(v.y, h1, l1);
                bsplit(v.z, h2, l2); bsplit(v.w, h3, l3);
                uint2 ph = make_uint2((unsigned)h0 | ((unsigned)h1 << 16),
                                      (unsigned)h2 | ((unsigned)h3 << 16));
                uint2 pl = make_uint2((unsigned)l0 | ((unsigned)l1 << 16),
                                      (unsigned)l2 | ((unsigned)l3 << 16));
                *(uint2*)(bhp + c * 4) = ph;
                *(uint2*)(blp + c * 4) = pl;
            }
            if (tid < BFs) csh[tid] = cb[f0 + tid];
        }
        __syncthreads();

        f32x4 acc[4][2];
#pragma unroll
        for (int i = 0; i < 4; ++i)
#pragma unroll
            for (int j = 0; j < 2; ++j) acc[i][j] = (f32x4){0.f, 0.f, 0.f, 0.f};

#pragma unroll
        for (int ks = 0; ks < 4; ++ks) {
            int kb = ks * 32 + quad * 8;
            short8 bh0 = *(const short8*)&Bh[(wn * 32 + lane15) * LDB + kb];
            short8 bl0 = *(const short8*)&Bl[(wn * 32 + lane15) * LDB + kb];
            short8 bh1 = *(const short8*)&Bh[(wn * 32 + 16 + lane15) * LDB + kb];
            short8 bl1 = *(const short8*)&Bl[(wn * 32 + 16 + lane15) * LDB + kb];
#pragma unroll
            for (int i = 0; i < 4; ++i) {
                acc[i][0] = __builtin_amdgcn_mfma_f32_16x16x32_bf16(ah[i][ks], bh0, acc[i][0], 0, 0, 0);
                acc[i][0] = __builtin_amdgcn_mfma_f32_16x16x32_bf16(al[i][ks], bh0, acc[i][0], 0, 0, 0);
                acc[i][0] = __builtin_amdgcn_mfma_f32_16x16x32_bf16(ah[i][ks], bl0, acc[i][0], 0, 0, 0);
                acc[i][1] = __builtin_amdgcn_mfma_f32_16x16x32_bf16(ah[i][ks], bh1, acc[i][1], 0, 0, 0);
                acc[i][1] = __builtin_amdgcn_mfma_f32_16x16x32_bf16(al[i][ks], bh1, acc[i][1], 0, 0, 0);
                acc[i][1] = __builtin_amdgcn_mfma_f32_16x16x32_bf16(ah[i][ks], bl1, acc[i][1], 0, 0, 0);
            }
        }

#pragma unroll
        for (int j = 0; j < 2; ++j) {
            float cj = csh[wn * 32 + j * 16 + lane15];
#pragma unroll
            for (int i = 0; i < 4; ++i)
#pragma unroll
                for (int rr = 0; rr < 4; ++rr)
                    mmax[i][rr] = fmaxf(mmax[i][rr], acc[i][j][rr] + cj);
        }
        __syncthreads();
    }

    float* red = (float*)Bh;   // [128][33]
#pragma unroll
    for (int i = 0; i < 4; ++i)
#pragma unroll
        for (int rr = 0; rr < 4; ++rr) {
            int row = wm * 64 + i * 16 + quad * 4 + rr;
            red[row * 33 + wn * 16 + lane15] = mmax[i][rr];
        }
    __syncthreads();
    if (tid < BMs) {
        float m = red[tid * 33];
#pragma unroll
        for (int c = 1; c < 32; ++c) m = fmaxf(m, red[tid * 33 + c]);
        int n = nblk * BMs + tid;
        float v = (n < nb_entities[b]) ? expf(m - 0.5f * ent_norm[(size_t)b * Nn + n]) : 0.0f;
        sp[n] = v;
    }
}

// ---------------- K5: top-K per (b, r), stable-descending like jax.lax.top_k ----------------
__global__ void k_topk(const float* __restrict__ sp0, const float* __restrict__ sp1,
                       float* __restrict__ z_scores, int* __restrict__ z_idx) {
    int b = blockIdx.x, r = blockIdx.y;
    const float* sp = ((r == 0) ? sp0 : sp1) + (size_t)b * Nn;
    __shared__ float vals[Nn];
    __shared__ float bv[256];
    __shared__ int   bi[256];
    int tid = threadIdx.x;
    for (int i = tid; i < Nn; i += 256) vals[i] = sp[i];
    __syncthreads();
    for (int k = 0; k < Kk; ++k) {
        float best = -1.0f; int bidx = Nn;
        for (int i = tid; i < Nn; i += 256) {
            float v = vals[i];
            if (v > best) { best = v; bidx = i; }
        }
        bv[tid] = best; bi[tid] = bidx;
        __syncthreads();
        for (int s = 128; s > 0; s >>= 1) {
            if (tid < s) {
                float v2 = bv[tid + s]; int i2 = bi[tid + s];
                if (v2 > bv[tid] || (v2 == bv[tid] && i2 < bi[tid])) { bv[tid] = v2; bi[tid] = i2; }
            }
            __syncthreads();
        }
        if (tid == 0) {
            z_scores[((size_t)b * 2 + r) * Kk + k] = bv[0];
            z_idx[((size_t)b * 2 + r) * Kk + k]    = bi[0];
            vals[bi[0]] = -1.0f;
        }
        __syncthreads();
    }
}

// ---------------- K6: second hop rescore — thread-per-fact, all K beams at once ----------------
// score[k][f] = (s2b[f] - 0.5*|fa_f|^2) + z_k . fa_f - 0.5*|z_k|^2 ; partial max over chunk.
__global__ __launch_bounds__(256) void k_s2(
    const float* __restrict__ ent, const float* __restrict__ fa1,
    const float* __restrict__ fa2, const float* __restrict__ s2b0,
    const float* __restrict__ s2b1, const int* __restrict__ z_idx,
    float* __restrict__ partial /* [b][r][S2FC][Kk] */) {
    int fc = blockIdx.x, b = blockIdx.y, r = blockIdx.z;
    const float* factX = (r == 0) ? fa1 : fa2;   // z compares vs fa1 (r=0) / fa2 (r=1)
    const float* s2b   = ((r == 0) ? s2b0 : s2b1) + (size_t)b * Ff;

    __shared__ float zsh[Kk][Ee];
    __shared__ float znorm[Kk];
    __shared__ int   zish[Kk];
    __shared__ float red[4][Kk];

    int tid = threadIdx.x;
    if (tid < Kk) zish[tid] = z_idx[((size_t)b * 2 + r) * Kk + tid];
    __syncthreads();
    for (int idx = tid; idx < Kk * Ee; idx += 256) {
        int k = idx >> 7, e = idx & 127;
        zsh[k][e] = ent[((size_t)b * Nn + zish[k]) * Ee + e];
    }
    __syncthreads();
    if (tid < Kk) {
        float s = 0.f;
        for (int e = 0; e < Ee; ++e) { float v = zsh[tid][e]; s += v * v; }
        znorm[tid] = s;
    }
    __syncthreads();

    int f = fc * S2F + tid;
    const float* fp = factX + ((size_t)b * Ff + f) * Ee;
    float acc[Kk];
#pragma unroll
    for (int k = 0; k < Kk; ++k) acc[k] = 0.f;
    float nf = 0.f;
#pragma unroll 4
    for (int e0 = 0; e0 < Ee; e0 += 4) {
        float4 v = *(const float4*)(fp + e0);
        nf += v.x * v.x + v.y * v.y + v.z * v.z + v.w * v.w;
#pragma unroll
        for (int k = 0; k < Kk; ++k) {
            float4 z = *(const float4*)&zsh[k][e0];
            acc[k] += z.x * v.x + z.y * v.y + z.z * v.z + z.w * v.w;
        }
    }
    float base = s2b[f] - 0.5f * nf;   // -INF for invalid facts
    float sc[Kk];
#pragma unroll
    for (int k = 0; k < Kk; ++k) sc[k] = base + acc[k] - 0.5f * znorm[k];
    // wave max-reduce each k, then cross-wave via LDS
    for (int o = 32; o; o >>= 1)
#pragma unroll
        for (int k = 0; k < Kk; ++k) sc[k] = fmaxf(sc[k], __shfl_down(sc[k], o));
    int wv = tid >> 6;
    if ((tid & 63) == 0)
#pragma unroll
        for (int k = 0; k < Kk; ++k) red[wv][k] = sc[k];
    __syncthreads();
    if (tid < Kk) {
        float m = fmaxf(fmaxf(red[0][tid], red[1][tid]), fmaxf(red[2][tid], red[3][tid]));
        partial[(((size_t)b * 2 + r) * S2FC + fc) * Kk + tid] = m;
    }
}

// ---------------- K7: final combine ----------------
__global__ void k_final(const float* __restrict__ lsc0, const float* __restrict__ partial,
                        const float* __restrict__ z_scores, float* __restrict__ out) {
    int b = blockIdx.x, tid = threadIdx.x;
    __shared__ float sm[256];
    float m = -INFINITY;
    for (int f = tid; f < Ff; f += 256) m = fmaxf(m, lsc0[(size_t)b * Ff + f]);
    sm[tid] = m;
    __syncthreads();
    for (int s = 128; s > 0; s >>= 1) {
        if (tid < s) sm[tid] = fmaxf(sm[tid], sm[tid + s]);
        __syncthreads();
    }
    if (tid == 0) {
        float sc0 = expf(sm[0]);
        float g = -INFINITY;
        for (int r = 0; r < 2; ++r)
            for (int k = 0; k < Kk; ++k) {
                float mm = -INFINITY;
                for (int fc = 0; fc < S2FC; ++fc)
                    mm = fmaxf(mm, partial[(((size_t)b * 2 + r) * S2FC + fc) * Kk + k]);
                float rule = fminf(expf(mm), z_scores[((size_t)b * 2 + r) * Kk + k]);
                g = fmaxf(g, rule);
            }
        out[b] = fmaxf(sc0, g);
    }
}

extern "C" void kernel_launch(void* const* d_in, const int* in_sizes, int n_in,
                              void* d_out, int out_size, void* d_ws, size_t ws_size,
                              hipStream_t stream) {
    const float* rel  = (const float*)d_in[0];
    const float* arg1 = (const float*)d_in[1];
    const float* arg2 = (const float*)d_in[2];
    const float* frel = (const float*)d_in[3];
    const float* fa1  = (const float*)d_in[4];
    const float* fa2  = (const float*)d_in[5];
    const float* ent  = (const float*)d_in[6];
    const float* hopW = (const float*)d_in[7];
    const float* hopb = (const float*)d_in[8];
    const int* nb_facts    = (const int*)d_in[9];
    const int* nb_entities = (const int*)d_in[10];
    float* out = (float*)d_out;

    float* ws = (float*)d_ws;
    size_t off = 0;
    float* h        = ws + off; off += 4 * Bb * Ee;
    float* c0       = ws + off; off += (size_t)Bb * Ff;
    float* c1       = ws + off; off += (size_t)Bb * Ff;
    float* s2b0     = ws + off; off += (size_t)Bb * Ff;
    float* s2b1     = ws + off; off += (size_t)Bb * Ff;
    float* lsc0     = ws + off; off += (size_t)Bb * Ff;
    float* sp0      = ws + off; off += (size_t)Bb * Nn;
    float* sp1      = ws + off; off += (size_t)Bb * Nn;
    float* ent_norm = ws + off; off += (size_t)Bb * Nn;
    float* z_scores = ws + off; off += Bb * 2 * Kk;
    float* partial  = ws + off; off += (size_t)Bb * 2 * S2FC * Kk;
    int*   z_idx    = (int*)(ws + off); off += Bb * 2 * Kk;

    k_hops<<<dim3(4, Bb), 128, 0, stream>>>(rel, hopW, hopb, h);
    k_entnorm<<<dim3(Bb * Nn / 4), 256, 0, stream>>>(ent, ent_norm);
    k_facts<<<dim3(Ff, Bb), 64, 0, stream>>>(rel, arg1, arg2, frel, fa1, fa2, h,
                                             nb_facts, c0, c1, s2b0, s2b1, lsc0);
    k_spmax_mfma<<<dim3(Nn / BMs, Bb, 2), 256, 0, stream>>>(ent, fa1, fa2, c0, c1, ent_norm,
                                                            nb_entities, sp0, sp1);
    k_topk<<<dim3(Bb, 2), 256, 0, stream>>>(sp0, sp1, z_scores, z_idx);
    k_s2<<<dim3(S2FC, Bb, 2), 256, 0, stream>>>(ent, fa1, fa2, s2b0, s2b1, z_idx, partial);
    k_final<<<dim3(Bb), 256, 0, stream>>>(lsc0, partial, z_scores, out);
}

// Round 4
// 271.564 us; speedup vs baseline: 3.2412x; 1.0978x over previous
//
#include <hip/hip_runtime.h>
#include <math.h>

#define Bb 16
#define Nn 2048
#define Ff 2048
#define Ee 128
#define Kk 10
#define S2FC 8              // fact chunks in k_s2
#define S2F (Ff / S2FC)     // 256 facts per block

typedef __attribute__((ext_vector_type(8))) short short8;
typedef __attribute__((ext_vector_type(4))) float f32x4;

// ---------------- helpers ----------------
__device__ inline float wave_sum(float x) {
    for (int o = 32; o; o >>= 1) x += __shfl_down(x, o);
    return x;  // valid in lane 0
}

// split fp32 -> bf16 hi (truncate) + bf16 lo (truncate of exact remainder)
__device__ inline void bsplit(float x, unsigned short& h, unsigned short& l) {
    unsigned int u = __float_as_uint(x);
    h = (unsigned short)(u >> 16);
    float hf = __uint_as_float(u & 0xFFFF0000u);
    l = (unsigned short)(__float_as_uint(x - hf) >> 16);
}

// ---------------- K0: pre-split facts into MFMA-fragment order ----------------
// dst unit g=(b,oct,f): 16 ushorts = {hi[8], lo[8]} of src[b][f][oct*8..oct*8+8)
__global__ __launch_bounds__(256) void k_bsplit(
    const float* __restrict__ fa1, const float* __restrict__ fa2,
    unsigned short* __restrict__ B0, unsigned short* __restrict__ B1) {
    int g = blockIdx.x * 256 + threadIdx.x;       // b*32768 + oct*2048 + f
    const float* src = (blockIdx.y == 0) ? fa2 : fa1;    // r=0 scans fa2, r=1 scans fa1
    unsigned short* dst = ((blockIdx.y == 0) ? B0 : B1) + (size_t)g * 16;
    int f = g & 2047, oct = (g >> 11) & 15, b = g >> 15;
    const float* s = src + ((size_t)b * Ff + f) * Ee + oct * 8;
    float4 v0 = *(const float4*)s;
    float4 v1 = *(const float4*)(s + 4);
    float xs[8] = {v0.x, v0.y, v0.z, v0.w, v1.x, v1.y, v1.z, v1.w};
    unsigned short hi[8], lo[8];
#pragma unroll
    for (int j = 0; j < 8; ++j) bsplit(xs[j], hi[j], lo[j]);
    uint4 ph, pl;
    ph.x = (unsigned)hi[0] | ((unsigned)hi[1] << 16);
    ph.y = (unsigned)hi[2] | ((unsigned)hi[3] << 16);
    ph.z = (unsigned)hi[4] | ((unsigned)hi[5] << 16);
    ph.w = (unsigned)hi[6] | ((unsigned)hi[7] << 16);
    pl.x = (unsigned)lo[0] | ((unsigned)lo[1] << 16);
    pl.y = (unsigned)lo[2] | ((unsigned)lo[3] << 16);
    pl.z = (unsigned)lo[4] | ((unsigned)lo[5] << 16);
    pl.w = (unsigned)lo[6] | ((unsigned)lo[7] << 16);
    *(uint4*)dst = ph;
    *(uint4*)(dst + 8) = pl;
}

// ---------------- K1: hop projections h[rj][b][e] = rel[b] @ W[rj] + bias ----------------
__global__ void k_hops(const float* __restrict__ rel, const float* __restrict__ hop_W,
                       const float* __restrict__ hop_b, float* __restrict__ h) {
    int rj = blockIdx.x;      // 0..3  (r*2 + j)
    int b  = blockIdx.y;
    int e  = threadIdx.x;     // 0..127
    const float* W  = hop_W + (size_t)rj * Ee * Ee;
    const float* rb = rel + b * Ee;
    float acc = hop_b[rj * Ee + e];
    for (int i = 0; i < Ee; ++i) acc += rb[i] * W[i * Ee + e];
    h[((size_t)rj * Bb + b) * Ee + e] = acc;
}

// ---------------- K2: entity self-norms ----------------
__global__ void k_entnorm(const float* __restrict__ ent, float* __restrict__ ent_norm) {
    int row  = blockIdx.x * 4 + (threadIdx.x >> 6);   // B*N rows
    int lane = threadIdx.x & 63;
    const float* p = ent + (size_t)row * Ee;
    float a = p[lane], c = p[lane + 64];
    float s = wave_sum(a * a + c * c);
    if (lane == 0) ent_norm[row] = s;
}

// ---------------- K3: per-fact query distances -> c0,c1,s2b0,s2b1,lsc0 ----------------
__global__ void k_facts(const float* __restrict__ rel, const float* __restrict__ arg1,
                        const float* __restrict__ arg2, const float* __restrict__ frel,
                        const float* __restrict__ fa1, const float* __restrict__ fa2,
                        const float* __restrict__ h, const int* __restrict__ nb_facts,
                        float* __restrict__ c0, float* __restrict__ c1,
                        float* __restrict__ s2b0, float* __restrict__ s2b1,
                        float* __restrict__ lsc0) {
    int f = blockIdx.x, b = blockIdx.y;
    int lane = threadIdx.x;            // block = 64
    size_t fb = ((size_t)b * Ff + f) * Ee;
    float d_rr = 0, d_a11 = 0, d_a22 = 0, d_h10 = 0, d_h11 = 0, d_h20 = 0, d_h21 = 0;
    float d_a12 = 0, d_a21 = 0, n1 = 0, n2 = 0;
#pragma unroll
    for (int half = 0; half < 2; ++half) {
        int e = lane + half * 64;
        float vr = frel[fb + e], v1 = fa1[fb + e], v2 = fa2[fb + e];
        float qr = rel[b * Ee + e], q1 = arg1[b * Ee + e], q2 = arg2[b * Ee + e];
        float h10 = h[((size_t)0 * Bb + b) * Ee + e];
        float h20 = h[((size_t)1 * Bb + b) * Ee + e];
        float h11 = h[((size_t)2 * Bb + b) * Ee + e];
        float h21 = h[((size_t)3 * Bb + b) * Ee + e];
        float t;
        t = qr - vr;  d_rr  += t * t;
        t = q1 - v1;  d_a11 += t * t;
        t = q2 - v2;  d_a22 += t * t;
        t = h10 - vr; d_h10 += t * t;
        t = h11 - vr; d_h11 += t * t;
        t = h20 - vr; d_h20 += t * t;
        t = h21 - vr; d_h21 += t * t;
        t = q1 - v2;  d_a12 += t * t;
        t = q2 - v1;  d_a21 += t * t;
        n1 += v1 * v1; n2 += v2 * v2;
    }
    d_rr = wave_sum(d_rr);   d_a11 = wave_sum(d_a11); d_a22 = wave_sum(d_a22);
    d_h10 = wave_sum(d_h10); d_h11 = wave_sum(d_h11); d_h20 = wave_sum(d_h20);
    d_h21 = wave_sum(d_h21); d_a12 = wave_sum(d_a12); d_a21 = wave_sum(d_a21);
    n1 = wave_sum(n1);       n2 = wave_sum(n2);
    if (lane == 0) {
        bool valid = f < nb_facts[b];
        const float NI = -INFINITY;
        size_t o = (size_t)b * Ff + f;
        lsc0[o] = valid ? -0.5f * (d_rr + d_a11 + d_a22) : NI;
        c0[o]   = valid ? (-0.5f * (d_h10 + d_a11 + n2)) : NI;
        c1[o]   = valid ? (-0.5f * (d_h11 + d_a12 + n1)) : NI;
        s2b0[o] = valid ? (-0.5f * (d_h20 + d_a22)) : NI;
        s2b1[o] = valid ? (-0.5f * (d_h21 + d_a21)) : NI;
    }
}

// ---------------- K4: fused bias+max GEMM, B frags direct from global (no LDS loop) ----
#define BMs 128

__global__ __launch_bounds__(256, 2) void k_spmax_mfma(
    const float* __restrict__ ent, const unsigned short* __restrict__ B0,
    const unsigned short* __restrict__ B1, const float* __restrict__ c0,
    const float* __restrict__ c1, const float* __restrict__ ent_norm,
    const int* __restrict__ nb_entities, float* __restrict__ sp0,
    float* __restrict__ sp1) {
    int nblk = blockIdx.x, b = blockIdx.y, r = blockIdx.z;
    const unsigned short* Bt = (r == 0) ? B0 : B1;
    const float* cb = ((r == 0) ? c0 : c1) + (size_t)b * Ff;
    float* sp = ((r == 0) ? sp0 : sp1) + (size_t)b * Nn;

    int tid = threadIdx.x;
    int wave = tid >> 6, lane = tid & 63;
    int wm = wave >> 1, wn = wave & 1;
    int lane15 = lane & 15, quad = lane >> 4;

    // ---- A fragments in registers (hi/lo split), reused across all facts ----
    short8 ah[4][4], al[4][4];
    {
        const float* abase = ent + ((size_t)b * Nn + (size_t)nblk * BMs + wm * 64) * Ee;
#pragma unroll
        for (int i = 0; i < 4; ++i)
#pragma unroll
            for (int ks = 0; ks < 4; ++ks) {
                const float* p = abase + (size_t)(i * 16 + lane15) * Ee + ks * 32 + quad * 8;
                float4 v0 = *(const float4*)p;
                float4 v1 = *(const float4*)(p + 4);
                float xs[8] = {v0.x, v0.y, v0.z, v0.w, v1.x, v1.y, v1.z, v1.w};
#pragma unroll
                for (int j = 0; j < 8; ++j) {
                    unsigned short hh, ll;
                    bsplit(xs[j], hh, ll);
                    ah[i][ks][j] = (short)hh;
                    al[i][ks][j] = (short)ll;
                }
            }
    }

    // wave-invariant B base: unit (b, oct=quad, row=wn*32+lane15), stride per ks = 4 octs
    const unsigned short* bbase =
        Bt + ((((size_t)b * 16 + quad) * Ff) + wn * 32 + lane15) * 16;

    float mmax[4][4];
#pragma unroll
    for (int i = 0; i < 4; ++i)
#pragma unroll
        for (int rr = 0; rr < 4; ++rr) mmax[i][rr] = -INFINITY;

    for (int f0 = 0; f0 < Ff; f0 += 64) {
        f32x4 acc[4][2];
#pragma unroll
        for (int i = 0; i < 4; ++i)
#pragma unroll
            for (int j = 0; j < 2; ++j) acc[i][j] = (f32x4){0.f, 0.f, 0.f, 0.f};

#pragma unroll
        for (int ks = 0; ks < 4; ++ks) {
            const unsigned short* p0 = bbase + (size_t)ks * 4 * Ff * 16 + (size_t)f0 * 16;
            const unsigned short* p1 = p0 + 16 * 16;
            short8 bh0 = *(const short8*)p0;
            short8 bl0 = *(const short8*)(p0 + 8);
            short8 bh1 = *(const short8*)p1;
            short8 bl1 = *(const short8*)(p1 + 8);
#pragma unroll
            for (int i = 0; i < 4; ++i) {
                acc[i][0] = __builtin_amdgcn_mfma_f32_16x16x32_bf16(ah[i][ks], bh0, acc[i][0], 0, 0, 0);
                acc[i][0] = __builtin_amdgcn_mfma_f32_16x16x32_bf16(al[i][ks], bh0, acc[i][0], 0, 0, 0);
                acc[i][0] = __builtin_amdgcn_mfma_f32_16x16x32_bf16(ah[i][ks], bl0, acc[i][0], 0, 0, 0);
                acc[i][1] = __builtin_amdgcn_mfma_f32_16x16x32_bf16(ah[i][ks], bh1, acc[i][1], 0, 0, 0);
                acc[i][1] = __builtin_amdgcn_mfma_f32_16x16x32_bf16(al[i][ks], bh1, acc[i][1], 0, 0, 0);
                acc[i][1] = __builtin_amdgcn_mfma_f32_16x16x32_bf16(ah[i][ks], bl1, acc[i][1], 0, 0, 0);
            }
        }

#pragma unroll
        for (int j = 0; j < 2; ++j) {
            float cj = cb[f0 + wn * 32 + j * 16 + lane15];
#pragma unroll
            for (int i = 0; i < 4; ++i)
#pragma unroll
                for (int rr = 0; rr < 4; ++rr)
                    mmax[i][rr] = fmaxf(mmax[i][rr], acc[i][j][rr] + cj);
        }
    }

    // ---- reduce across the 16 lane15 columns in-wave, then across wn via LDS ----
    __shared__ float red[BMs][2];
#pragma unroll
    for (int i = 0; i < 4; ++i)
#pragma unroll
        for (int rr = 0; rr < 4; ++rr) {
            float v = mmax[i][rr];
#pragma unroll
            for (int m = 1; m < 16; m <<= 1) v = fmaxf(v, __shfl_xor(v, m));
            if (lane15 == 0) red[wm * 64 + i * 16 + quad * 4 + rr][wn] = v;
        }
    __syncthreads();
    if (tid < BMs) {
        float m = fmaxf(red[tid][0], red[tid][1]);
        int n = nblk * BMs + tid;
        float v = (n < nb_entities[b]) ? expf(m - 0.5f * ent_norm[(size_t)b * Nn + n]) : 0.0f;
        sp[n] = v;
    }
}

// ---------------- K5: top-K per (b, r), stable-descending like jax.lax.top_k ----------------
__global__ void k_topk(const float* __restrict__ sp0, const float* __restrict__ sp1,
                       float* __restrict__ z_scores, int* __restrict__ z_idx) {
    int b = blockIdx.x, r = blockIdx.y;
    const float* sp = ((r == 0) ? sp0 : sp1) + (size_t)b * Nn;
    __shared__ float vals[Nn];
    __shared__ float bv[256];
    __shared__ int   bi[256];
    int tid = threadIdx.x;
    for (int i = tid; i < Nn; i += 256) vals[i] = sp[i];
    __syncthreads();
    for (int k = 0; k < Kk; ++k) {
        float best = -1.0f; int bidx = Nn;
        for (int i = tid; i < Nn; i += 256) {
            float v = vals[i];
            if (v > best) { best = v; bidx = i; }
        }
        bv[tid] = best; bi[tid] = bidx;
        __syncthreads();
        for (int s = 128; s > 0; s >>= 1) {
            if (tid < s) {
                float v2 = bv[tid + s]; int i2 = bi[tid + s];
                if (v2 > bv[tid] || (v2 == bv[tid] && i2 < bi[tid])) { bv[tid] = v2; bi[tid] = i2; }
            }
            __syncthreads();
        }
        if (tid == 0) {
            z_scores[((size_t)b * 2 + r) * Kk + k] = bv[0];
            z_idx[((size_t)b * 2 + r) * Kk + k]    = bi[0];
            vals[bi[0]] = -1.0f;
        }
        __syncthreads();
    }
}

// ---------------- K6: second hop rescore — thread-per-fact, all K beams at once ----------------
__global__ __launch_bounds__(256) void k_s2(
    const float* __restrict__ ent, const float* __restrict__ fa1,
    const float* __restrict__ fa2, const float* __restrict__ s2b0,
    const float* __restrict__ s2b1, const int* __restrict__ z_idx,
    float* __restrict__ partial /* [b][r][S2FC][Kk] */) {
    int fc = blockIdx.x, b = blockIdx.y, r = blockIdx.z;
    const float* factX = (r == 0) ? fa1 : fa2;   // z compares vs fa1 (r=0) / fa2 (r=1)
    const float* s2b   = ((r == 0) ? s2b0 : s2b1) + (size_t)b * Ff;

    __shared__ float zsh[Kk][Ee];
    __shared__ float znorm[Kk];
    __shared__ int   zish[Kk];
    __shared__ float red[4][Kk];

    int tid = threadIdx.x;
    if (tid < Kk) zish[tid] = z_idx[((size_t)b * 2 + r) * Kk + tid];
    __syncthreads();
    for (int idx = tid; idx < Kk * Ee; idx += 256) {
        int k = idx >> 7, e = idx & 127;
        zsh[k][e] = ent[((size_t)b * Nn + zish[k]) * Ee + e];
    }
    __syncthreads();
    if (tid < Kk) {
        float s = 0.f;
        for (int e = 0; e < Ee; ++e) { float v = zsh[tid][e]; s += v * v; }
        znorm[tid] = s;
    }
    __syncthreads();

    int f = fc * S2F + tid;
    const float* fp = factX + ((size_t)b * Ff + f) * Ee;
    float acc[Kk];
#pragma unroll
    for (int k = 0; k < Kk; ++k) acc[k] = 0.f;
    float nf = 0.f;
#pragma unroll 4
    for (int e0 = 0; e0 < Ee; e0 += 4) {
        float4 v = *(const float4*)(fp + e0);
        nf += v.x * v.x + v.y * v.y + v.z * v.z + v.w * v.w;
#pragma unroll
        for (int k = 0; k < Kk; ++k) {
            float4 z = *(const float4*)&zsh[k][e0];
            acc[k] += z.x * v.x + z.y * v.y + z.z * v.z + z.w * v.w;
        }
    }
    float base = s2b[f] - 0.5f * nf;   // -INF for invalid facts
    float sc[Kk];
#pragma unroll
    for (int k = 0; k < Kk; ++k) sc[k] = base + acc[k] - 0.5f * znorm[k];
    for (int o = 32; o; o >>= 1)
#pragma unroll
        for (int k = 0; k < Kk; ++k) sc[k] = fmaxf(sc[k], __shfl_down(sc[k], o));
    int wv = tid >> 6;
    if ((tid & 63) == 0)
#pragma unroll
        for (int k = 0; k < Kk; ++k) red[wv][k] = sc[k];
    __syncthreads();
    if (tid < Kk) {
        float m = fmaxf(fmaxf(red[0][tid], red[1][tid]), fmaxf(red[2][tid], red[3][tid]));
        partial[(((size_t)b * 2 + r) * S2FC + fc) * Kk + tid] = m;
    }
}

// ---------------- K7: final combine ----------------
__global__ void k_final(const float* __restrict__ lsc0, const float* __restrict__ partial,
                        const float* __restrict__ z_scores, float* __restrict__ out) {
    int b = blockIdx.x, tid = threadIdx.x;
    __shared__ float sm[256];
    float m = -INFINITY;
    for (int f = tid; f < Ff; f += 256) m = fmaxf(m, lsc0[(size_t)b * Ff + f]);
    sm[tid] = m;
    __syncthreads();
    for (int s = 128; s > 0; s >>= 1) {
        if (tid < s) sm[tid] = fmaxf(sm[tid], sm[tid + s]);
        __syncthreads();
    }
    if (tid == 0) {
        float sc0 = expf(sm[0]);
        float g = -INFINITY;
        for (int r = 0; r < 2; ++r)
            for (int k = 0; k < Kk; ++k) {
                float mm = -INFINITY;
                for (int fc = 0; fc < S2FC; ++fc)
                    mm = fmaxf(mm, partial[(((size_t)b * 2 + r) * S2FC + fc) * Kk + k]);
                float rule = fminf(expf(mm), z_scores[((size_t)b * 2 + r) * Kk + k]);
                g = fmaxf(g, rule);
            }
        out[b] = fmaxf(sc0, g);
    }
}

extern "C" void kernel_launch(void* const* d_in, const int* in_sizes, int n_in,
                              void* d_out, int out_size, void* d_ws, size_t ws_size,
                              hipStream_t stream) {
    const float* rel  = (const float*)d_in[0];
    const float* arg1 = (const float*)d_in[1];
    const float* arg2 = (const float*)d_in[2];
    const float* frel = (const float*)d_in[3];
    const float* fa1  = (const float*)d_in[4];
    const float* fa2  = (const float*)d_in[5];
    const float* ent  = (const float*)d_in[6];
    const float* hopW = (const float*)d_in[7];
    const float* hopb = (const float*)d_in[8];
    const int* nb_facts    = (const int*)d_in[9];
    const int* nb_entities = (const int*)d_in[10];
    float* out = (float*)d_out;

    float* ws = (float*)d_ws;
    size_t off = 0;
    float* h        = ws + off; off += 4 * Bb * Ee;
    float* c0       = ws + off; off += (size_t)Bb * Ff;
    float* c1       = ws + off; off += (size_t)Bb * Ff;
    float* s2b0     = ws + off; off += (size_t)Bb * Ff;
    float* s2b1     = ws + off; off += (size_t)Bb * Ff;
    float* lsc0     = ws + off; off += (size_t)Bb * Ff;
    float* sp0      = ws + off; off += (size_t)Bb * Nn;
    float* sp1      = ws + off; off += (size_t)Bb * Nn;
    float* ent_norm = ws + off; off += (size_t)Bb * Nn;
    float* z_scores = ws + off; off += Bb * 2 * Kk;
    float* partial  = ws + off; off += (size_t)Bb * 2 * S2FC * Kk;
    int*   z_idx    = (int*)(ws + off); off += Bb * 2 * Kk;
    off = (off + 7) & ~(size_t)7;   // 32B-align the split tensors
    unsigned short* B0 = (unsigned short*)(ws + off); off += (size_t)Bb * 16 * Ff * 8;  // 16.8MB
    unsigned short* B1 = (unsigned short*)(ws + off); off += (size_t)Bb * 16 * Ff * 8;

    k_bsplit<<<dim3(Bb * 16 * Ff / 256, 2), 256, 0, stream>>>(fa1, fa2, B0, B1);
    k_hops<<<dim3(4, Bb), 128, 0, stream>>>(rel, hopW, hopb, h);
    k_entnorm<<<dim3(Bb * Nn / 4), 256, 0, stream>>>(ent, ent_norm);
    k_facts<<<dim3(Ff, Bb), 64, 0, stream>>>(rel, arg1, arg2, frel, fa1, fa2, h,
                                             nb_facts, c0, c1, s2b0, s2b1, lsc0);
    k_spmax_mfma<<<dim3(Nn / BMs, Bb, 2), 256, 0, stream>>>(ent, B0, B1, c0, c1, ent_norm,
                                                            nb_entities, sp0, sp1);
    k_topk<<<dim3(Bb, 2), 256, 0, stream>>>(sp0, sp1, z_scores, z_idx);
    k_s2<<<dim3(S2FC, Bb, 2), 256, 0, stream>>>(ent, fa1, fa2, s2b0, s2b1, z_idx, partial);
    k_final<<<dim3(Bb), 256, 0, stream>>>(lsc0, partial, z_scores, out);
}

// Round 5
// 264.272 us; speedup vs baseline: 3.3306x; 1.0276x over previous
//
#include <hip/hip_runtime.h>
#include <math.h>

#define Bb 16
#define Nn 2048
#define Ff 2048
#define Ee 128
#define Kk 10
#define S2FC 8              // fact chunks in k_s2
#define S2F (Ff / S2FC)     // 256 facts per block

typedef __attribute__((ext_vector_type(8))) short short8;
typedef __attribute__((ext_vector_type(4))) float f32x4;

// ---------------- helpers ----------------
__device__ inline float wave_sum(float x) {
    for (int o = 32; o; o >>= 1) x += __shfl_down(x, o);
    return x;  // valid in lane 0
}

// split fp32 -> bf16 hi (truncate) + bf16 lo (truncate of exact remainder)
__device__ inline void bsplit(float x, unsigned short& h, unsigned short& l) {
    unsigned int u = __float_as_uint(x);
    h = (unsigned short)(u >> 16);
    float hf = __uint_as_float(u & 0xFFFF0000u);
    l = (unsigned short)(__float_as_uint(x - hf) >> 16);
}

// ---------------- K0: pre-split facts into MFMA-fragment order (coalesced both sides) ----
// dst unit (b,oct,f): 16 ushorts = {hi[8], lo[8]} of src[b][f][oct*8..oct*8+8)
__global__ __launch_bounds__(256) void k_bsplit(
    const float* __restrict__ fa1, const float* __restrict__ fa2,
    unsigned short* __restrict__ B0, unsigned short* __restrict__ B1) {
    int tid = threadIdx.x;
    int oct = tid & 15, fl = tid >> 4;        // oct fastest -> coalesced reads
    int bx = blockIdx.x;                      // b*128 + fblk
    int b = bx >> 7, f = (bx & 127) * 16 + fl;
    const float* src = (blockIdx.y == 0) ? fa2 : fa1;    // r=0 scans fa2, r=1 scans fa1
    unsigned short* dst = ((blockIdx.y == 0) ? B0 : B1) +
                          (((size_t)b * 16 + oct) * Ff + f) * 16;
    const float* s = src + ((size_t)b * Ff + f) * Ee + oct * 8;
    float4 v0 = *(const float4*)s;
    float4 v1 = *(const float4*)(s + 4);
    float xs[8] = {v0.x, v0.y, v0.z, v0.w, v1.x, v1.y, v1.z, v1.w};
    unsigned short hi[8], lo[8];
#pragma unroll
    for (int j = 0; j < 8; ++j) bsplit(xs[j], hi[j], lo[j]);
    uint4 ph, pl;
    ph.x = (unsigned)hi[0] | ((unsigned)hi[1] << 16);
    ph.y = (unsigned)hi[2] | ((unsigned)hi[3] << 16);
    ph.z = (unsigned)hi[4] | ((unsigned)hi[5] << 16);
    ph.w = (unsigned)hi[6] | ((unsigned)hi[7] << 16);
    pl.x = (unsigned)lo[0] | ((unsigned)lo[1] << 16);
    pl.y = (unsigned)lo[2] | ((unsigned)lo[3] << 16);
    pl.z = (unsigned)lo[4] | ((unsigned)lo[5] << 16);
    pl.w = (unsigned)lo[6] | ((unsigned)lo[7] << 16);
    *(uint4*)dst = ph;
    *(uint4*)(dst + 8) = pl;
}

// ---------------- K1: hop projections ----------------
__global__ void k_hops(const float* __restrict__ rel, const float* __restrict__ hop_W,
                       const float* __restrict__ hop_b, float* __restrict__ h) {
    int rj = blockIdx.x;
    int b  = blockIdx.y;
    int e  = threadIdx.x;
    const float* W  = hop_W + (size_t)rj * Ee * Ee;
    const float* rb = rel + b * Ee;
    float acc = hop_b[rj * Ee + e];
    for (int i = 0; i < Ee; ++i) acc += rb[i] * W[i * Ee + e];
    h[((size_t)rj * Bb + b) * Ee + e] = acc;
}

// ---------------- K2: entity self-norms ----------------
__global__ void k_entnorm(const float* __restrict__ ent, float* __restrict__ ent_norm) {
    int row  = blockIdx.x * 4 + (threadIdx.x >> 6);
    int lane = threadIdx.x & 63;
    const float* p = ent + (size_t)row * Ee;
    float a = p[lane], c = p[lane + 64];
    float s = wave_sum(a * a + c * c);
    if (lane == 0) ent_norm[row] = s;
}

// ---------------- K3: per-fact query distances ----------------
__global__ void k_facts(const float* __restrict__ rel, const float* __restrict__ arg1,
                        const float* __restrict__ arg2, const float* __restrict__ frel,
                        const float* __restrict__ fa1, const float* __restrict__ fa2,
                        const float* __restrict__ h, const int* __restrict__ nb_facts,
                        float* __restrict__ c0, float* __restrict__ c1,
                        float* __restrict__ s2b0, float* __restrict__ s2b1,
                        float* __restrict__ lsc0) {
    int f = blockIdx.x, b = blockIdx.y;
    int lane = threadIdx.x;
    size_t fb = ((size_t)b * Ff + f) * Ee;
    float d_rr = 0, d_a11 = 0, d_a22 = 0, d_h10 = 0, d_h11 = 0, d_h20 = 0, d_h21 = 0;
    float d_a12 = 0, d_a21 = 0, n1 = 0, n2 = 0;
#pragma unroll
    for (int half = 0; half < 2; ++half) {
        int e = lane + half * 64;
        float vr = frel[fb + e], v1 = fa1[fb + e], v2 = fa2[fb + e];
        float qr = rel[b * Ee + e], q1 = arg1[b * Ee + e], q2 = arg2[b * Ee + e];
        float h10 = h[((size_t)0 * Bb + b) * Ee + e];
        float h20 = h[((size_t)1 * Bb + b) * Ee + e];
        float h11 = h[((size_t)2 * Bb + b) * Ee + e];
        float h21 = h[((size_t)3 * Bb + b) * Ee + e];
        float t;
        t = qr - vr;  d_rr  += t * t;
        t = q1 - v1;  d_a11 += t * t;
        t = q2 - v2;  d_a22 += t * t;
        t = h10 - vr; d_h10 += t * t;
        t = h11 - vr; d_h11 += t * t;
        t = h20 - vr; d_h20 += t * t;
        t = h21 - vr; d_h21 += t * t;
        t = q1 - v2;  d_a12 += t * t;
        t = q2 - v1;  d_a21 += t * t;
        n1 += v1 * v1; n2 += v2 * v2;
    }
    d_rr = wave_sum(d_rr);   d_a11 = wave_sum(d_a11); d_a22 = wave_sum(d_a22);
    d_h10 = wave_sum(d_h10); d_h11 = wave_sum(d_h11); d_h20 = wave_sum(d_h20);
    d_h21 = wave_sum(d_h21); d_a12 = wave_sum(d_a12); d_a21 = wave_sum(d_a21);
    n1 = wave_sum(n1);       n2 = wave_sum(n2);
    if (lane == 0) {
        bool valid = f < nb_facts[b];
        const float NI = -INFINITY;
        size_t o = (size_t)b * Ff + f;
        lsc0[o] = valid ? -0.5f * (d_rr + d_a11 + d_a22) : NI;
        c0[o]   = valid ? (-0.5f * (d_h10 + d_a11 + n2)) : NI;
        c1[o]   = valid ? (-0.5f * (d_h11 + d_a12 + n1)) : NI;
        s2b0[o] = valid ? (-0.5f * (d_h20 + d_a22)) : NI;
        s2b1[o] = valid ? (-0.5f * (d_h21 + d_a21)) : NI;
    }
}

// ---------------- K4: fused bias+max GEMM, chunk-prefetched B, A-lo in LDS ----------------
#define BMs 128

__global__ __launch_bounds__(256, 2) void k_spmax_mfma(
    const float* __restrict__ ent, const unsigned short* __restrict__ B0,
    const unsigned short* __restrict__ B1, const float* __restrict__ c0,
    const float* __restrict__ c1, const float* __restrict__ ent_norm,
    const int* __restrict__ nb_entities, float* __restrict__ sp0,
    float* __restrict__ sp1) {
    int nblk = blockIdx.x, b = blockIdx.y, r = blockIdx.z;
    const unsigned short* Bt = (r == 0) ? B0 : B1;
    const float* cb = ((r == 0) ? c0 : c1) + (size_t)b * Ff;
    float* sp = ((r == 0) ? sp0 : sp1) + (size_t)b * Nn;

    __shared__ unsigned short alds[2 * 4 * 4 * 64 * 8];   // 32KB: [wm][i][ks][lane]x8

    int tid = threadIdx.x;
    int wave = tid >> 6, lane = tid & 63;
    int wm = wave >> 1, wn = wave & 1;
    int lane15 = lane & 15, quad = lane >> 4;

    // ---- A-hi fragments in registers; A-lo staged once to LDS ----
    short8 ah[4][4];
    {
        const float* abase = ent + ((size_t)b * Nn + (size_t)nblk * BMs + wm * 64) * Ee;
#pragma unroll
        for (int i = 0; i < 4; ++i)
#pragma unroll
            for (int ks = 0; ks < 4; ++ks) {
                const float* p = abase + (size_t)(i * 16 + lane15) * Ee + ks * 32 + quad * 8;
                float4 v0 = *(const float4*)p;
                float4 v1 = *(const float4*)(p + 4);
                float xs[8] = {v0.x, v0.y, v0.z, v0.w, v1.x, v1.y, v1.z, v1.w};
                short8 hi8, lo8;
#pragma unroll
                for (int j = 0; j < 8; ++j) {
                    unsigned short hh, ll;
                    bsplit(xs[j], hh, ll);
                    hi8[j] = (short)hh;
                    lo8[j] = (short)ll;
                }
                ah[i][ks] = hi8;
                if (wn == 0)
                    *(short8*)&alds[(((wm * 4 + i) * 4 + ks) * 64 + lane) * 8] = lo8;
            }
    }
    __syncthreads();

    // wave-invariant B base: unit (b, oct=ks*4+quad, row=wn*32+lane15)
    const unsigned short* bbase =
        Bt + ((((size_t)b * 16 + quad) * Ff) + wn * 32 + lane15) * 16;

    // ---- prefetch chunk 0's B fragments ----
    short8 pbh0[4], pbl0[4], pbh1[4], pbl1[4];
#pragma unroll
    for (int ks = 0; ks < 4; ++ks) {
        const unsigned short* p0 = bbase + ((size_t)ks * 4 * Ff) * 16;
        pbh0[ks] = *(const short8*)p0;
        pbl0[ks] = *(const short8*)(p0 + 8);
        pbh1[ks] = *(const short8*)(p0 + 256);
        pbl1[ks] = *(const short8*)(p0 + 264);
    }

    float mmax[4][4];
#pragma unroll
    for (int i = 0; i < 4; ++i)
#pragma unroll
        for (int rr = 0; rr < 4; ++rr) mmax[i][rr] = -INFINITY;

    for (int c = 0; c < 32; ++c) {
        int f0 = c * 64;
        float cj0 = cb[f0 + wn * 32 + lane15];
        float cj1 = cb[f0 + wn * 32 + 16 + lane15];
        f32x4 acc[4][2];
#pragma unroll
        for (int i = 0; i < 4; ++i) {
            acc[i][0] = (f32x4){cj0, cj0, cj0, cj0};   // bias pre-loaded into accumulator
            acc[i][1] = (f32x4){cj1, cj1, cj1, cj1};
        }
        int fn = ((c + 1) & 31) * 64;   // wraps on last chunk (harmless redundant load)

#pragma unroll
        for (int ks = 0; ks < 4; ++ks) {
            short8 bh0 = pbh0[ks], bl0 = pbl0[ks], bh1 = pbh1[ks], bl1 = pbl1[ks];
            // prefetch next chunk, same ks (stays in flight across this ks's MFMAs)
            const unsigned short* p0 = bbase + ((size_t)ks * 4 * Ff + fn) * 16;
            pbh0[ks] = *(const short8*)p0;
            pbl0[ks] = *(const short8*)(p0 + 8);
            pbh1[ks] = *(const short8*)(p0 + 256);
            pbl1[ks] = *(const short8*)(p0 + 264);
            // A-lo fragments from LDS
            short8 al0 = *(short8*)&alds[(((wm * 4 + 0) * 4 + ks) * 64 + lane) * 8];
            short8 al1 = *(short8*)&alds[(((wm * 4 + 1) * 4 + ks) * 64 + lane) * 8];
            short8 al2 = *(short8*)&alds[(((wm * 4 + 2) * 4 + ks) * 64 + lane) * 8];
            short8 al3 = *(short8*)&alds[(((wm * 4 + 3) * 4 + ks) * 64 + lane) * 8];
            short8 alv[4] = {al0, al1, al2, al3};
#pragma unroll
            for (int i = 0; i < 4; ++i) {
                acc[i][0] = __builtin_amdgcn_mfma_f32_16x16x32_bf16(ah[i][ks], bh0, acc[i][0], 0, 0, 0);
                acc[i][0] = __builtin_amdgcn_mfma_f32_16x16x32_bf16(alv[i],    bh0, acc[i][0], 0, 0, 0);
                acc[i][0] = __builtin_amdgcn_mfma_f32_16x16x32_bf16(ah[i][ks], bl0, acc[i][0], 0, 0, 0);
                acc[i][1] = __builtin_amdgcn_mfma_f32_16x16x32_bf16(ah[i][ks], bh1, acc[i][1], 0, 0, 0);
                acc[i][1] = __builtin_amdgcn_mfma_f32_16x16x32_bf16(alv[i],    bh1, acc[i][1], 0, 0, 0);
                acc[i][1] = __builtin_amdgcn_mfma_f32_16x16x32_bf16(ah[i][ks], bl1, acc[i][1], 0, 0, 0);
            }
        }

#pragma unroll
        for (int j = 0; j < 2; ++j)
#pragma unroll
            for (int i = 0; i < 4; ++i)
#pragma unroll
                for (int rr = 0; rr < 4; ++rr)
                    mmax[i][rr] = fmaxf(mmax[i][rr], acc[i][j][rr]);
    }

    // ---- reduce across 16 lane15 columns in-wave, then across wn via LDS (reuse alds) ----
    __syncthreads();
    float* red = (float*)alds;   // [128][2]
#pragma unroll
    for (int i = 0; i < 4; ++i)
#pragma unroll
        for (int rr = 0; rr < 4; ++rr) {
            float v = mmax[i][rr];
#pragma unroll
            for (int m = 1; m < 16; m <<= 1) v = fmaxf(v, __shfl_xor(v, m));
            if (lane15 == 0) red[(wm * 64 + i * 16 + quad * 4 + rr) * 2 + wn] = v;
        }
    __syncthreads();
    if (tid < BMs) {
        float m = fmaxf(red[tid * 2], red[tid * 2 + 1]);
        int n = nblk * BMs + tid;
        float v = (n < nb_entities[b]) ? expf(m - 0.5f * ent_norm[(size_t)b * Nn + n]) : 0.0f;
        sp[n] = v;
    }
}

// ---------------- K5: top-K per (b, r) — single wave, barrier-free, jax-stable ties ----
__global__ void k_topk(const float* __restrict__ sp0, const float* __restrict__ sp1,
                       float* __restrict__ z_scores, int* __restrict__ z_idx) {
    int b = blockIdx.x, r = blockIdx.y;
    const float* sp = ((r == 0) ? sp0 : sp1) + (size_t)b * Nn;
    int lane = threadIdx.x;   // block = 64
    float v[Nn / 64];
#pragma unroll
    for (int i = 0; i < Nn / 64; ++i) v[i] = sp[i * 64 + lane];
    for (int k = 0; k < Kk; ++k) {
        float best = -INFINITY; int bidx = 0;
#pragma unroll
        for (int i = 0; i < Nn / 64; ++i)
            if (v[i] > best) { best = v[i]; bidx = i * 64 + lane; }   // strict > keeps lowest idx
#pragma unroll
        for (int m = 1; m < 64; m <<= 1) {
            float ov = __shfl_xor(best, m);
            int oi = __shfl_xor(bidx, m);
            if (ov > best || (ov == best && oi < bidx)) { best = ov; bidx = oi; }
        }
        if (lane == 0) {
            z_scores[((size_t)b * 2 + r) * Kk + k] = best;
            z_idx[((size_t)b * 2 + r) * Kk + k]    = bidx;
        }
        if ((bidx & 63) == lane) {
            int slot = bidx >> 6;
#pragma unroll
            for (int i = 0; i < Nn / 64; ++i)
                if (i == slot) v[i] = -INFINITY;
        }
    }
}

// ---------------- K6: second hop rescore — thread-per-fact, all K beams at once ----------------
__global__ __launch_bounds__(256) void k_s2(
    const float* __restrict__ ent, const float* __restrict__ fa1,
    const float* __restrict__ fa2, const float* __restrict__ s2b0,
    const float* __restrict__ s2b1, const int* __restrict__ z_idx,
    float* __restrict__ partial /* [b][r][S2FC][Kk] */) {
    int fc = blockIdx.x, b = blockIdx.y, r = blockIdx.z;
    const float* factX = (r == 0) ? fa1 : fa2;
    const float* s2b   = ((r == 0) ? s2b0 : s2b1) + (size_t)b * Ff;

    __shared__ float zsh[Kk][Ee];
    __shared__ float znorm[Kk];
    __shared__ int   zish[Kk];
    __shared__ float red[4][Kk];

    int tid = threadIdx.x;
    if (tid < Kk) zish[tid] = z_idx[((size_t)b * 2 + r) * Kk + tid];
    __syncthreads();
    for (int idx = tid; idx < Kk * Ee; idx += 256) {
        int k = idx >> 7, e = idx & 127;
        zsh[k][e] = ent[((size_t)b * Nn + zish[k]) * Ee + e];
    }
    __syncthreads();
    if (tid < Kk) {
        float s = 0.f;
        for (int e = 0; e < Ee; ++e) { float v = zsh[tid][e]; s += v * v; }
        znorm[tid] = s;
    }
    __syncthreads();

    int f = fc * S2F + tid;
    const float* fp = factX + ((size_t)b * Ff + f) * Ee;
    float acc[Kk];
#pragma unroll
    for (int k = 0; k < Kk; ++k) acc[k] = 0.f;
    float nf = 0.f;
#pragma unroll 4
    for (int e0 = 0; e0 < Ee; e0 += 4) {
        float4 v = *(const float4*)(fp + e0);
        nf += v.x * v.x + v.y * v.y + v.z * v.z + v.w * v.w;
#pragma unroll
        for (int k = 0; k < Kk; ++k) {
            float4 z = *(const float4*)&zsh[k][e0];
            acc[k] += z.x * v.x + z.y * v.y + z.z * v.z + z.w * v.w;
        }
    }
    float base = s2b[f] - 0.5f * nf;
    float sc[Kk];
#pragma unroll
    for (int k = 0; k < Kk; ++k) sc[k] = base + acc[k] - 0.5f * znorm[k];
    for (int o = 32; o; o >>= 1)
#pragma unroll
        for (int k = 0; k < Kk; ++k) sc[k] = fmaxf(sc[k], __shfl_down(sc[k], o));
    int wv = tid >> 6;
    if ((tid & 63) == 0)
#pragma unroll
        for (int k = 0; k < Kk; ++k) red[wv][k] = sc[k];
    __syncthreads();
    if (tid < Kk) {
        float m = fmaxf(fmaxf(red[0][tid], red[1][tid]), fmaxf(red[2][tid], red[3][tid]));
        partial[(((size_t)b * 2 + r) * S2FC + fc) * Kk + tid] = m;
    }
}

// ---------------- K7: final combine ----------------
__global__ void k_final(const float* __restrict__ lsc0, const float* __restrict__ partial,
                        const float* __restrict__ z_scores, float* __restrict__ out) {
    int b = blockIdx.x, tid = threadIdx.x;
    __shared__ float sm[256];
    float m = -INFINITY;
    for (int f = tid; f < Ff; f += 256) m = fmaxf(m, lsc0[(size_t)b * Ff + f]);
    sm[tid] = m;
    __syncthreads();
    for (int s = 128; s > 0; s >>= 1) {
        if (tid < s) sm[tid] = fmaxf(sm[tid], sm[tid + s]);
        __syncthreads();
    }
    if (tid == 0) {
        float sc0 = expf(sm[0]);
        float g = -INFINITY;
        for (int r = 0; r < 2; ++r)
            for (int k = 0; k < Kk; ++k) {
                float mm = -INFINITY;
                for (int fc = 0; fc < S2FC; ++fc)
                    mm = fmaxf(mm, partial[(((size_t)b * 2 + r) * S2FC + fc) * Kk + k]);
                float rule = fminf(expf(mm), z_scores[((size_t)b * 2 + r) * Kk + k]);
                g = fmaxf(g, rule);
            }
        out[b] = fmaxf(sc0, g);
    }
}

extern "C" void kernel_launch(void* const* d_in, const int* in_sizes, int n_in,
                              void* d_out, int out_size, void* d_ws, size_t ws_size,
                              hipStream_t stream) {
    const float* rel  = (const float*)d_in[0];
    const float* arg1 = (const float*)d_in[1];
    const float* arg2 = (const float*)d_in[2];
    const float* frel = (const float*)d_in[3];
    const float* fa1  = (const float*)d_in[4];
    const float* fa2  = (const float*)d_in[5];
    const float* ent  = (const float*)d_in[6];
    const float* hopW = (const float*)d_in[7];
    const float* hopb = (const float*)d_in[8];
    const int* nb_facts    = (const int*)d_in[9];
    const int* nb_entities = (const int*)d_in[10];
    float* out = (float*)d_out;

    float* ws = (float*)d_ws;
    size_t off = 0;
    float* h        = ws + off; off += 4 * Bb * Ee;
    float* c0       = ws + off; off += (size_t)Bb * Ff;
    float* c1       = ws + off; off += (size_t)Bb * Ff;
    float* s2b0     = ws + off; off += (size_t)Bb * Ff;
    float* s2b1     = ws + off; off += (size_t)Bb * Ff;
    float* lsc0     = ws + off; off += (size_t)Bb * Ff;
    float* sp0      = ws + off; off += (size_t)Bb * Nn;
    float* sp1      = ws + off; off += (size_t)Bb * Nn;
    float* ent_norm = ws + off; off += (size_t)Bb * Nn;
    float* z_scores = ws + off; off += Bb * 2 * Kk;
    float* partial  = ws + off; off += (size_t)Bb * 2 * S2FC * Kk;
    int*   z_idx    = (int*)(ws + off); off += Bb * 2 * Kk;
    off = (off + 7) & ~(size_t)7;   // 32B-align the split tensors
    unsigned short* B0 = (unsigned short*)(ws + off); off += (size_t)Bb * 16 * Ff * 8;
    unsigned short* B1 = (unsigned short*)(ws + off); off += (size_t)Bb * 16 * Ff * 8;

    k_bsplit<<<dim3(Bb * Ff / 16, 2), 256, 0, stream>>>(fa1, fa2, B0, B1);
    k_hops<<<dim3(4, Bb), 128, 0, stream>>>(rel, hopW, hopb, h);
    k_entnorm<<<dim3(Bb * Nn / 4), 256, 0, stream>>>(ent, ent_norm);
    k_facts<<<dim3(Ff, Bb), 64, 0, stream>>>(rel, arg1, arg2, frel, fa1, fa2, h,
                                             nb_facts, c0, c1, s2b0, s2b1, lsc0);
    k_spmax_mfma<<<dim3(Nn / BMs, Bb, 2), 256, 0, stream>>>(ent, B0, B1, c0, c1, ent_norm,
                                                            nb_entities, sp0, sp1);
    k_topk<<<dim3(Bb, 2), 64, 0, stream>>>(sp0, sp1, z_scores, z_idx);
    k_s2<<<dim3(S2FC, Bb, 2), 256, 0, stream>>>(ent, fa1, fa2, s2b0, s2b1, z_idx, partial);
    k_final<<<dim3(Bb), 256, 0, stream>>>(lsc0, partial, z_scores, out);
}